// Round 9
// baseline (226.456 us; speedup 1.0000x reference)
//
#include <hip/hip_runtime.h>
#include <hip/hip_bf16.h>
#include <stdint.h>

#define SEQ 4096
#define HID 1152
#define NH  16
#define HD  72
#define N3  3456
#define DQ  80      // Q padded head dim (5 x 16)
#define QBLK 256    // q rows per block (4 wg x 64 q; 8 waves = 4 wg x 2 kh)
#define TILE_ELEMS 14336  // 28KB tile image: K 64x256B = 16KB, V 96x128B = 12KB

typedef __bf16 bf16;
typedef __bf16 bf16x8 __attribute__((ext_vector_type(8)));
typedef float  f32x4  __attribute__((ext_vector_type(4)));
typedef float  f32x16 __attribute__((ext_vector_type(16)));
typedef uint32_t u32x4 __attribute__((ext_vector_type(4)));

#define EXP2F(x) __builtin_amdgcn_exp2f(x)
#define PLSWAP(a, b) asm("v_permlane32_swap_b32 %0, %1" : "+v"(a), "+v"(b))

__device__ __forceinline__ void gload_lds16(const void* g, void* l) {
    __builtin_amdgcn_global_load_lds(
        (__attribute__((address_space(1))) void*)(void*)g,
        (__attribute__((address_space(3))) void*)l, 16, 0, 0);
}
__device__ __forceinline__ uint16_t bfbits(float x) {
    return __builtin_bit_cast(uint16_t, (bf16)x);
}

// bijective XCD swizzle (nwg % 8 == 0 for every launch below)
__device__ __forceinline__ int xcd_swz(int orig, int nwg) {
    return (orig & 7) * (nwg >> 3) + (orig >> 3);
}

// ---------------- elementwise f32 -> bf16 (8/thread) ----------------
__global__ void cvt_bf16(const float* __restrict__ in, bf16* __restrict__ out, int n8)
{
    int i = blockIdx.x * 256 + threadIdx.x;
    if (i >= n8) return;
    const float4* p = (const float4*)in + (size_t)i * 2;
    float4 a = p[0], b = p[1];
    bf16x8 o;
    o[0]=(bf16)a.x; o[1]=(bf16)a.y; o[2]=(bf16)a.z; o[3]=(bf16)a.w;
    o[4]=(bf16)b.x; o[5]=(bf16)b.y; o[6]=(bf16)b.z; o[7]=(bf16)b.w;
    ((bf16x8*)out)[i] = o;
}

// ---------------- [R][C] f32 -> [C][R] bf16 (tiled transpose) ----------------
__global__ void transpose_cvt(const float* __restrict__ in, bf16* __restrict__ out, int R, int C)
{
    __shared__ float tl[32][33];
    int c0 = blockIdx.x * 32, r0 = blockIdx.y * 32;
    int tx = threadIdx.x & 31, ty = threadIdx.x >> 5;
#pragma unroll
    for (int i = 0; i < 4; ++i)
        tl[ty + 8*i][tx] = in[(size_t)(r0 + ty + 8*i) * C + c0 + tx];
    __syncthreads();
#pragma unroll
    for (int i = 0; i < 4; ++i)
        out[(size_t)(c0 + ty + 8*i) * R + r0 + tx] = (bf16)tl[tx][ty + 8*i];
}

// ---------------- GEMM: C[M][N] = A[M][K] * BT[N][K]^T + bias ----------------
template<int OUT_F32>
__global__ __launch_bounds__(256)
void gemm_bt(const bf16* __restrict__ A, const bf16* __restrict__ BT,
             const float* __restrict__ bias, void* __restrict__ out,
             int M, int N, int K)
{
    __shared__ __align__(16) bf16 As[128 * 32];
    __shared__ __align__(16) bf16 Bs[128 * 32];
    int tid = threadIdx.x;
    int lane = tid & 63, w = tid >> 6;
    int wm = w & 1, wn = w >> 1;
    int nwg  = gridDim.x * gridDim.y;
    int wgid = xcd_swz(blockIdx.y * gridDim.x + blockIdx.x, nwg);
    int m0 = (wgid % gridDim.x) * 128, n0 = (wgid / gridDim.x) * 128;
    int lq = lane & 15, lk = lane >> 4;

    f32x4 acc[4][4] = {};

    for (int k0 = 0; k0 < K; k0 += 32) {
        __syncthreads();
#pragma unroll
        for (int i = 0; i < 2; ++i) {
            int c = w * 128 + i * 64 + lane;
            const bf16* ga = A  + (size_t)(m0 + (c >> 2)) * K + k0 + (c & 3) * 8;
            const bf16* gb = BT + (size_t)(n0 + (c >> 2)) * K + k0 + (c & 3) * 8;
            gload_lds16(ga, (char*)As + (w * 128 + i * 64) * 16);
            gload_lds16(gb, (char*)Bs + (w * 128 + i * 64) * 16);
        }
        __syncthreads();
        bf16x8 af[4], bfr[4];
#pragma unroll
        for (int m = 0; m < 4; ++m)
            af[m] = *(const bf16x8*)&As[(wm * 64 + m * 16 + lq) * 32 + lk * 8];
#pragma unroll
        for (int n = 0; n < 4; ++n)
            bfr[n] = *(const bf16x8*)&Bs[(wn * 64 + n * 16 + lq) * 32 + lk * 8];
#pragma unroll
        for (int m = 0; m < 4; ++m)
#pragma unroll
            for (int n = 0; n < 4; ++n)
                acc[m][n] = __builtin_amdgcn_mfma_f32_16x16x32_bf16(af[m], bfr[n], acc[m][n], 0, 0, 0);
    }

    int rb = m0 + wm * 64, cb = n0 + wn * 64;
#pragma unroll
    for (int m = 0; m < 4; ++m) {
#pragma unroll
        for (int n = 0; n < 4; ++n) {
            int col = cb + n * 16 + lq;
            float b = bias[col];
#pragma unroll
            for (int r = 0; r < 4; ++r) {
                int row = rb + m * 16 + lk * 4 + r;
                float v = acc[m][n][r] + b;
                if (OUT_F32) ((float*)out)[(size_t)row * N + col] = v;
                else         ((bf16*)out)[(size_t)row * N + col] = (bf16)v;
            }
        }
    }
}

// ---- RoPE + pack: Qp [h][s][80] (scale*log2e folded); K into KVp tile image ----
// KVp[h][t][14336 elem]: elems 0..8191 = K image (64 keys x 16 chunks, chunk
// swizzled = dchunk ^ (key&15)); elems 8192..14335 = V image (96 rows x 8 chunks).
__global__ void rope_pack_qk3(const bf16* __restrict__ qkv, const float* __restrict__ cs,
                              const float* __restrict__ sn, bf16* __restrict__ Qp,
                              bf16* __restrict__ KVp)
{
    int idx = blockIdx.x * 256 + threadIdx.x;    // NH*SEQ*128
    int dd = idx & 127;
    int s  = (idx >> 7) & (SEQ - 1);
    int h  = idx >> 19;
    float qv = 0.f, kv = 0.f;
    if (dd < HD) {
        const bf16* row = qkv + (size_t)s * N3 + h * HD;
        float c  = cs[s * HD + dd], si = sn[s * HD + dd];
        int   dp = (dd < 36) ? dd + 36 : dd - 36;
        float sg = (dd < 36) ? -1.f : 1.f;
        float qa = (float)row[dd],       qb = (float)row[dp];
        float ka = (float)row[HID + dd], kb = (float)row[HID + dp];
        qv = (qa * c + sg * qb * si) * (0.11785113019775793f * 1.4426950408889634f);
        kv =  ka * c + sg * kb * si;
    }
    int t = s >> 6, key = s & 63;
    int chunk = key * 16 + ((dd >> 3) ^ (key & 15));
    KVp[((size_t)(h * 64 + t)) * TILE_ELEMS + chunk * 8 + (dd & 7)] = (bf16)kv;
    if (dd < DQ) Qp[((size_t)h * SEQ + s) * DQ + dd] = (bf16)qv;
}

// ---- pack V into KVp tile image: chunk (d*8+cpos) holds keys (cpos^(d&7))*8.. at dim d ----
// d 0..71 = data; d 72 = ones (l via MFMA); d 73..95 = zero
__global__ void pack_v3(const bf16* __restrict__ qkv, bf16* __restrict__ KVp)
{
    __shared__ __align__(16) bf16 tl[64][80];
    int h = blockIdx.y, t = blockIdx.x, s0 = t * 64;
    int tid = threadIdx.x;
    for (int i = tid; i < 64 * 9; i += 256) {
        int key = i / 9, c8 = (i % 9) * 8;
        *(bf16x8*)&tl[key][c8] =
            *(const bf16x8*)&qkv[(size_t)(s0 + key) * N3 + 2 * HID + h * HD + c8];
    }
    __syncthreads();
    bf16* dst = KVp + ((size_t)(h * 64 + t)) * TILE_ELEMS + 8192;
    for (int vcid = tid; vcid < 768; vcid += 256) {     // 96 rows x 8 chunks
        int d = vcid >> 3, cpos = vcid & 7;
        int kb8 = (cpos ^ (d & 7)) << 3;
        bf16x8 v;
#pragma unroll
        for (int j = 0; j < 8; ++j)
            v[j] = (d < HD) ? tl[kb8 + j][d] : ((d == HD) ? (bf16)1.f : (bf16)0.f);
        *(bf16x8*)&dst[vcid * 8] = v;
    }
}

// ---- flash attention: 8 waves = 4 q-subtiles x 2 K-halves; 64 q per wave ----
// Each wave computes 64 q (two 32-q fragment sets A/B) so every K/V ds_read
// feeds 2 MFMAs (halves LDS traffic, the R8 bottleneck). K-split: kh=0/1 waves
// take even/odd 64-key tiles of a staged pair; no-max softmax makes partial
// (O,l) directly additive -> in-LDS merge, no rescale. Buffers at 0/65536;
// per-iteration buffer flip = XOR on precomputed address registers.
__global__ __launch_bounds__(512, 2)
void attn_fwd8(const bf16* __restrict__ Qp, const bf16* __restrict__ KVp,
               bf16* __restrict__ Oout)
{
    __shared__ __align__(16) char smem[131072];

    const int wgid = xcd_swz(blockIdx.x, gridDim.x);
    const int h  = wgid >> 4;
    const int q0 = (wgid & 15) * QBLK;
    const int tid = threadIdx.x, lane = tid & 63, w = tid >> 6;
    const int wg = w & 3, kh = w >> 2;
    const int ql = lane & 31, hi = lane >> 5;

    // Q fragments (B-operand), two 32-q sets per wave
    bf16x8 qfA[5], qfB[5];
    {
        const bf16* qa = Qp + ((size_t)h * SEQ + q0 + wg * 64 + ql) * DQ + hi * 8;
#pragma unroll
        for (int ks = 0; ks < 5; ++ks) {
            qfA[ks] = *(const bf16x8*)(qa + ks * 16);
            qfB[ks] = *(const bf16x8*)(qa + 32 * DQ + ks * 16);
        }
    }

    // precomputed swizzled LDS byte-offsets (flip bit16 per iteration)
    int aK[5], aV[4];
#pragma unroll
    for (int ks = 0; ks < 5; ++ks)
        aK[ks] = kh * 28672 + ql * 256 + (((ks * 2 + hi) ^ (ql & 15)) * 16);
#pragma unroll
    for (int u = 0; u < 4; ++u)
        aV[u] = kh * 28672 + 16384 + ql * 128 + (((u * 2 + hi) ^ (ql & 7)) * 16);

    f32x16 oA[3] = {}, oB[3] = {};   // O^T accum; V row 72 (ones) carries l

    const bf16* kvsrc = KVp + (size_t)h * (64 * TILE_ELEMS) + (size_t)tid * 8;

    // stage pair P (2 tiles = 56KB contiguous) into buffer at byte BASE
#define STAGE(P, BASE) do {                                                    \
        const bf16* s_ = kvsrc + (size_t)(P) * 28672;                          \
        char* d_ = smem + (BASE) + tid * 16;                                   \
        _Pragma("unroll")                                                      \
        for (int j_ = 0; j_ < 7; ++j_)                                         \
            gload_lds16(s_ + j_ * 4096, d_ + j_ * 8192);                       \
    } while (0)

    STAGE(0, 0);
    int stageBase = 65536;
    asm volatile("s_waitcnt vmcnt(0)" ::: "memory");
    __builtin_amdgcn_s_barrier();

    for (int t = 0; t < 32; ++t) {
        __builtin_amdgcn_sched_barrier(0);
        if (t + 1 < 32) STAGE(t + 1, stageBase);

        // ---- QK^T half 0 (keys 0..31 of my tile): one kf read -> 2 MFMAs ----
        f32x16 s0A = {}, s0B = {};
        __builtin_amdgcn_s_setprio(1);
#pragma unroll
        for (int ks = 0; ks < 5; ++ks) {
            bf16x8 kf = *(const bf16x8*)(smem + aK[ks]);
            s0A = __builtin_amdgcn_mfma_f32_32x32x16_bf16(kf, qfA[ks], s0A, 0, 0, 0);
            s0B = __builtin_amdgcn_mfma_f32_32x32x16_bf16(kf, qfB[ks], s0B, 0, 0, 0);
        }
        __builtin_amdgcn_s_setprio(0);
        uint32_t wA[16], wB[16];
#pragma unroll
        for (int i = 0; i < 8; ++i) {
            wA[i] = (uint32_t)bfbits(EXP2F(s0A[2*i])) | ((uint32_t)bfbits(EXP2F(s0A[2*i+1])) << 16);
            wB[i] = (uint32_t)bfbits(EXP2F(s0B[2*i])) | ((uint32_t)bfbits(EXP2F(s0B[2*i+1])) << 16);
        }

        // ---- QK^T half 1 (keys 32..63) ----
        f32x16 s1A = {}, s1B = {};
        __builtin_amdgcn_s_setprio(1);
#pragma unroll
        for (int ks = 0; ks < 5; ++ks) {
            bf16x8 kf = *(const bf16x8*)(smem + aK[ks] + 8192);
            s1A = __builtin_amdgcn_mfma_f32_32x32x16_bf16(kf, qfA[ks], s1A, 0, 0, 0);
            s1B = __builtin_amdgcn_mfma_f32_32x32x16_bf16(kf, qfB[ks], s1B, 0, 0, 0);
        }
        __builtin_amdgcn_s_setprio(0);
#pragma unroll
        for (int i = 0; i < 8; ++i) {
            wA[8+i] = (uint32_t)bfbits(EXP2F(s1A[2*i])) | ((uint32_t)bfbits(EXP2F(s1A[2*i+1])) << 16);
            wB[8+i] = (uint32_t)bfbits(EXP2F(s1B[2*i])) | ((uint32_t)bfbits(EXP2F(s1B[2*i+1])) << 16);
        }

        // ---- P fragments: key-halves exchange via permlane32_swap ----
        PLSWAP(wA[0], wA[2]);   PLSWAP(wA[1], wA[3]);
        PLSWAP(wA[4], wA[6]);   PLSWAP(wA[5], wA[7]);
        PLSWAP(wA[8], wA[10]);  PLSWAP(wA[9], wA[11]);
        PLSWAP(wA[12], wA[14]); PLSWAP(wA[13], wA[15]);
        PLSWAP(wB[0], wB[2]);   PLSWAP(wB[1], wB[3]);
        PLSWAP(wB[4], wB[6]);   PLSWAP(wB[5], wB[7]);
        PLSWAP(wB[8], wB[10]);  PLSWAP(wB[9], wB[11]);
        PLSWAP(wB[12], wB[14]); PLSWAP(wB[13], wB[15]);
        u32x4 uA0 = {wA[0],wA[1],wA[2],wA[3]},     uA1 = {wA[4],wA[5],wA[6],wA[7]};
        u32x4 uA2 = {wA[8],wA[9],wA[10],wA[11]},   uA3 = {wA[12],wA[13],wA[14],wA[15]};
        u32x4 uB0 = {wB[0],wB[1],wB[2],wB[3]},     uB1 = {wB[4],wB[5],wB[6],wB[7]};
        u32x4 uB2 = {wB[8],wB[9],wB[10],wB[11]},   uB3 = {wB[12],wB[13],wB[14],wB[15]};
        bf16x8 pA[4] = { __builtin_bit_cast(bf16x8, uA0), __builtin_bit_cast(bf16x8, uA1),
                         __builtin_bit_cast(bf16x8, uA2), __builtin_bit_cast(bf16x8, uA3) };
        bf16x8 pB[4] = { __builtin_bit_cast(bf16x8, uB0), __builtin_bit_cast(bf16x8, uB1),
                         __builtin_bit_cast(bf16x8, uB2), __builtin_bit_cast(bf16x8, uB3) };

        // ---- PV: one vf read -> 2 MFMAs (V row 72 = ones accumulates l) ----
        __builtin_amdgcn_s_setprio(1);
#pragma unroll
        for (int db = 0; db < 3; ++db) {
#pragma unroll
            for (int u = 0; u < 4; ++u) {
                bf16x8 vf = *(const bf16x8*)(smem + aV[u] + db * 4096);
                oA[db] = __builtin_amdgcn_mfma_f32_32x32x16_bf16(vf, pA[u], oA[db], 0, 0, 0);
                oB[db] = __builtin_amdgcn_mfma_f32_32x32x16_bf16(vf, pB[u], oB[db], 0, 0, 0);
            }
        }
        __builtin_amdgcn_s_setprio(0);

        __builtin_amdgcn_sched_barrier(0);
        asm volatile("s_waitcnt vmcnt(0)" ::: "memory");   // own staged loads landed
        __builtin_amdgcn_s_barrier();                      // current pair consumed
#pragma unroll
        for (int ks = 0; ks < 5; ++ks) aK[ks] ^= 65536;
#pragma unroll
        for (int u = 0; u < 4; ++u)    aV[u] ^= 65536;
        stageBase ^= 65536;
    }
#undef STAGE

    // ---- K-split merge: kh=1 partials added into kh=0 (pure add, no rescale) ----
    __syncthreads();
    float* M = (float*)smem;                      // [8 slots][64 lanes] stride 49
    const int slotA = ((wg * 2 + 0) * 64 + lane) * 49;
    const int slotB = ((wg * 2 + 1) * 64 + lane) * 49;
    if (kh == 1) {
#pragma unroll
        for (int db = 0; db < 3; ++db)
#pragma unroll
            for (int r = 0; r < 16; ++r) {
                M[slotA + db * 16 + r] = oA[db][r];
                M[slotB + db * 16 + r] = oB[db][r];
            }
    }
    __syncthreads();
    if (kh == 0) {
#pragma unroll
        for (int db = 0; db < 3; ++db)
#pragma unroll
            for (int r = 0; r < 16; ++r) {
                oA[db][r] += M[slotA + db * 16 + r];
                oB[db][r] += M[slotB + db * 16 + r];
            }
    }
    __syncthreads();

    // ---- epilogue: LDS transpose (stride 82 = 41 words, odd -> conflict-free) ----
    bf16* Os = (bf16*)smem;                        // [QBLK][82]
    if (kh == 0) {
        {
            float lv  = oA[2][4];                  // d=72 row holds l (hi=0 lanes)
            float lo_ = __shfl_xor(lv, 32);
            float invl = 1.0f / (hi ? lo_ : lv);
            int qloc = wg * 64 + ql;
#pragma unroll
            for (int db = 0; db < 3; ++db)
#pragma unroll
                for (int r = 0; r < 16; ++r) {
                    int dloc = (r & 3) + 8 * (r >> 2) + 4 * hi;
                    int d = db * 32 + dloc;
                    if (d < HD) Os[qloc * 82 + d] = (bf16)(oA[db][r] * invl);
                }
        }
        {
            float lv  = oB[2][4];
            float lo_ = __shfl_xor(lv, 32);
            float invl = 1.0f / (hi ? lo_ : lv);
            int qloc = wg * 64 + 32 + ql;
#pragma unroll
            for (int db = 0; db < 3; ++db)
#pragma unroll
                for (int r = 0; r < 16; ++r) {
                    int dloc = (r & 3) + 8 * (r >> 2) + 4 * hi;
                    int d = db * 32 + dloc;
                    if (d < HD) Os[qloc * 82 + d] = (bf16)(oB[db][r] * invl);
                }
        }
    }
    __syncthreads();
    for (int i = tid; i < QBLK * 36; i += 512) {
        int row = i / 36, c = i % 36;
        uint32_t val = *(const uint32_t*)((const char*)Os + row * 164 + c * 4);
        *(uint32_t*)((char*)Oout + (size_t)(q0 + row) * 2304 + h * 144 + c * 4) = val;
    }
}

extern "C" void kernel_launch(void* const* d_in, const int* in_sizes, int n_in,
                              void* d_out, int out_size, void* d_ws, size_t ws_size,
                              hipStream_t stream)
{
    const float* hidden = (const float*)d_in[0];
    // d_in[1] = cu_seqlens: unused by the reference
    const float* cosT  = (const float*)d_in[2];
    const float* sinT  = (const float*)d_in[3];
    const float* Wqkv  = (const float*)d_in[4];
    const float* bqkv  = (const float*)d_in[5];
    const float* Wproj = (const float*)d_in[6];
    const float* bproj = (const float*)d_in[7];

    char* ws = (char*)d_ws;
    size_t off = 0;
    auto alloc = [&](size_t bytes) {
        char* p = ws + off;
        off += (bytes + 255) & ~(size_t)255;
        return p;
    };
    bf16* hid_b  = (bf16*)alloc((size_t)SEQ * HID * 2);
    bf16* WqkvT  = (bf16*)alloc((size_t)N3  * HID * 2);
    bf16* WprojT = (bf16*)alloc((size_t)HID * HID * 2);
    bf16* qkv_b  = (bf16*)alloc((size_t)SEQ * N3  * 2);
    bf16* Qp     = (bf16*)alloc((size_t)NH * SEQ * DQ * 2);
    bf16* KVp    = (bf16*)alloc((size_t)NH * 64 * TILE_ELEMS * 2);
    bf16* attno  = hid_b;  // overlay: hid_b dead after GEMM1

    cvt_bf16<<<SEQ * HID / (256 * 8), 256, 0, stream>>>(hidden, hid_b, SEQ * HID / 8);
    transpose_cvt<<<dim3(N3 / 32, HID / 32), 256, 0, stream>>>(Wqkv, WqkvT, HID, N3);
    transpose_cvt<<<dim3(HID / 32, HID / 32), 256, 0, stream>>>(Wproj, WprojT, HID, HID);
    gemm_bt<0><<<dim3(SEQ / 128, N3 / 128), 256, 0, stream>>>(hid_b, WqkvT, bqkv, qkv_b,
                                                              SEQ, N3, HID);
    rope_pack_qk3<<<NH * SEQ * 128 / 256, 256, 0, stream>>>(qkv_b, cosT, sinT, Qp, KVp);
    pack_v3<<<dim3(SEQ / 64, NH), 256, 0, stream>>>(qkv_b, KVp);
    attn_fwd8<<<dim3(SEQ / QBLK * NH), 512, 0, stream>>>(Qp, KVp, attno);
    gemm_bt<1><<<dim3(SEQ / 128, HID / 128), 256, 0, stream>>>(attno, WprojT, bproj, d_out,
                                                               SEQ, HID, HID);
}

// Round 10
// 223.941 us; speedup vs baseline: 1.0112x; 1.0112x over previous
//
#include <hip/hip_runtime.h>
#include <hip/hip_bf16.h>
#include <stdint.h>

#define SEQ 4096
#define HID 1152
#define NH  16
#define HD  72
#define N3  3456
#define DQ  80      // Q padded head dim (5 x 16)
#define QBLK 256    // q rows per block (8 waves x 32)
#define TILE_ELEMS 14336  // 28KB tile image: K 64x256B = 16KB, V 96x128B = 12KB

typedef __bf16 bf16;
typedef __bf16 bf16x8 __attribute__((ext_vector_type(8)));
typedef float  f32x4  __attribute__((ext_vector_type(4)));
typedef float  f32x16 __attribute__((ext_vector_type(16)));
typedef uint32_t u32x4 __attribute__((ext_vector_type(4)));

#define EXP2F(x) __builtin_amdgcn_exp2f(x)
#define PLSWAP(a, b) asm("v_permlane32_swap_b32 %0, %1" : "+v"(a), "+v"(b))

__device__ __forceinline__ void gload_lds16(const void* g, void* l) {
    __builtin_amdgcn_global_load_lds(
        (__attribute__((address_space(1))) void*)(void*)g,
        (__attribute__((address_space(3))) void*)l, 16, 0, 0);
}
__device__ __forceinline__ uint16_t bfbits(float x) {
    return __builtin_bit_cast(uint16_t, (bf16)x);
}

// bijective XCD swizzle (nwg % 8 == 0 where used)
__device__ __forceinline__ int xcd_swz(int orig, int nwg) {
    return (orig & 7) * (nwg >> 3) + (orig >> 3);
}

// ---------------- fused prep: hidden f32->bf16 + both weight transposes ----------------
// blocks [0,2304): cvt hidden; [2304,6192): Wqkv^T; [6192,7488): Wproj^T
__global__ __launch_bounds__(256)
void prep(const float* __restrict__ hidden, const float* __restrict__ Wqkv,
          const float* __restrict__ Wproj, bf16* __restrict__ hid_b,
          bf16* __restrict__ WqkvT, bf16* __restrict__ WprojT)
{
    __shared__ float tl[32][33];
    int b = blockIdx.x, tid = threadIdx.x;
    if (b < 2304) {
        int i = b * 256 + tid;
        const float4* p = (const float4*)hidden + (size_t)i * 2;
        float4 a = p[0], c = p[1];
        bf16x8 o;
        o[0]=(bf16)a.x; o[1]=(bf16)a.y; o[2]=(bf16)a.z; o[3]=(bf16)a.w;
        o[4]=(bf16)c.x; o[5]=(bf16)c.y; o[6]=(bf16)c.z; o[7]=(bf16)c.w;
        ((bf16x8*)hid_b)[i] = o;
        return;
    }
    const float* in; bf16* out; int R, C, c0, r0;
    if (b < 6192) {
        int bb = b - 2304;
        in = Wqkv; out = WqkvT; R = HID; C = N3;
        c0 = (bb % 108) * 32; r0 = (bb / 108) * 32;
    } else {
        int bb = b - 6192;
        in = Wproj; out = WprojT; R = HID; C = HID;
        c0 = (bb % 36) * 32; r0 = (bb / 36) * 32;
    }
    int tx = tid & 31, ty = tid >> 5;
#pragma unroll
    for (int i = 0; i < 4; ++i)
        tl[ty + 8*i][tx] = in[(size_t)(r0 + ty + 8*i) * C + c0 + tx];
    __syncthreads();
#pragma unroll
    for (int i = 0; i < 4; ++i)
        out[(size_t)(c0 + ty + 8*i) * R + r0 + tx] = (bf16)tl[tx][ty + 8*i];
}

// ---------------- GEMM: C[M][N] = A[M][K] * BT[N][K]^T + bias ----------------
template<int OUT_F32>
__global__ __launch_bounds__(256)
void gemm_bt(const bf16* __restrict__ A, const bf16* __restrict__ BT,
             const float* __restrict__ bias, void* __restrict__ out,
             int M, int N, int K)
{
    __shared__ __align__(16) bf16 As[128 * 32];
    __shared__ __align__(16) bf16 Bs[128 * 32];
    int tid = threadIdx.x;
    int lane = tid & 63, w = tid >> 6;
    int wm = w & 1, wn = w >> 1;
    int nwg  = gridDim.x * gridDim.y;
    int wgid = xcd_swz(blockIdx.y * gridDim.x + blockIdx.x, nwg);
    int m0 = (wgid % gridDim.x) * 128, n0 = (wgid / gridDim.x) * 128;
    int lq = lane & 15, lk = lane >> 4;

    f32x4 acc[4][4] = {};

    for (int k0 = 0; k0 < K; k0 += 32) {
        __syncthreads();
#pragma unroll
        for (int i = 0; i < 2; ++i) {
            int c = w * 128 + i * 64 + lane;
            const bf16* ga = A  + (size_t)(m0 + (c >> 2)) * K + k0 + (c & 3) * 8;
            const bf16* gb = BT + (size_t)(n0 + (c >> 2)) * K + k0 + (c & 3) * 8;
            gload_lds16(ga, (char*)As + (w * 128 + i * 64) * 16);
            gload_lds16(gb, (char*)Bs + (w * 128 + i * 64) * 16);
        }
        __syncthreads();
        bf16x8 af[4], bfr[4];
#pragma unroll
        for (int m = 0; m < 4; ++m)
            af[m] = *(const bf16x8*)&As[(wm * 64 + m * 16 + lq) * 32 + lk * 8];
#pragma unroll
        for (int n = 0; n < 4; ++n)
            bfr[n] = *(const bf16x8*)&Bs[(wn * 64 + n * 16 + lq) * 32 + lk * 8];
#pragma unroll
        for (int m = 0; m < 4; ++m)
#pragma unroll
            for (int n = 0; n < 4; ++n)
                acc[m][n] = __builtin_amdgcn_mfma_f32_16x16x32_bf16(af[m], bfr[n], acc[m][n], 0, 0, 0);
    }

    int rb = m0 + wm * 64, cb = n0 + wn * 64;
#pragma unroll
    for (int m = 0; m < 4; ++m) {
#pragma unroll
        for (int n = 0; n < 4; ++n) {
            int col = cb + n * 16 + lq;
            float b = bias[col];
#pragma unroll
            for (int r = 0; r < 4; ++r) {
                int row = rb + m * 16 + lk * 4 + r;
                float v = acc[m][n][r] + b;
                if (OUT_F32) ((float*)out)[(size_t)row * N + col] = v;
                else         ((bf16*)out)[(size_t)row * N + col] = (bf16)v;
            }
        }
    }
}

// ---------------- fused pack: RoPE Q/K + V-transpose into KVp tile images ----------------
// blocks [0,32768): rope; [32768,33792): V pack.
// KVp[h][t][14336]: 0..8191 K image (chunk = key*16 + (dchunk^(key&15)));
// 8192..14335 V image (chunk d*8+cpos holds keys (cpos^(d&7))*8.. at dim d;
// d 0..71 data, 72 ones (l via MFMA), 73..95 zero).
__global__ __launch_bounds__(256)
void pack(const bf16* __restrict__ qkv, const float* __restrict__ cs,
          const float* __restrict__ sn, bf16* __restrict__ Qp,
          bf16* __restrict__ KVp)
{
    __shared__ __align__(16) bf16 tl[64][80];
    int b = blockIdx.x, tid = threadIdx.x;
    if (b < 32768) {
        int idx = b * 256 + tid;                 // NH*SEQ*128
        int dd = idx & 127;
        int s  = (idx >> 7) & (SEQ - 1);
        int h  = idx >> 19;
        float qv = 0.f, kv = 0.f;
        if (dd < HD) {
            const bf16* row = qkv + (size_t)s * N3 + h * HD;
            float c  = cs[s * HD + dd], si = sn[s * HD + dd];
            int   dp = (dd < 36) ? dd + 36 : dd - 36;
            float sg = (dd < 36) ? -1.f : 1.f;
            float qa = (float)row[dd],       qb = (float)row[dp];
            float ka = (float)row[HID + dd], kb = (float)row[HID + dp];
            qv = (qa * c + sg * qb * si) * (0.11785113019775793f * 1.4426950408889634f);
            kv =  ka * c + sg * kb * si;
        }
        int t = s >> 6, key = s & 63;
        int chunk = key * 16 + ((dd >> 3) ^ (key & 15));
        KVp[((size_t)(h * 64 + t)) * TILE_ELEMS + chunk * 8 + (dd & 7)] = (bf16)kv;
        if (dd < DQ) Qp[((size_t)h * SEQ + s) * DQ + dd] = (bf16)qv;
        return;
    }
    int bb = b - 32768;
    int t = bb & 63, h = bb >> 6, s0 = t * 64;
    for (int i = tid; i < 64 * 9; i += 256) {
        int key = i / 9, c8 = (i % 9) * 8;
        *(bf16x8*)&tl[key][c8] =
            *(const bf16x8*)&qkv[(size_t)(s0 + key) * N3 + 2 * HID + h * HD + c8];
    }
    __syncthreads();
    bf16* dst = KVp + ((size_t)(h * 64 + t)) * TILE_ELEMS + 8192;
    for (int vcid = tid; vcid < 768; vcid += 256) {     // 96 rows x 8 chunks
        int d = vcid >> 3, cpos = vcid & 7;
        int kb8 = (cpos ^ (d & 7)) << 3;
        bf16x8 v;
#pragma unroll
        for (int j = 0; j < 8; ++j)
            v[j] = (d < HD) ? tl[kb8 + j][d] : ((d == HD) ? (bf16)1.f : (bf16)0.f);
        *(bf16x8*)&dst[vcid * 8] = v;
    }
}

// ---- flash attention: 8 waves x 32q, 4 x 28KB buffers, counted-vmcnt pipeline ----
// Stage-ahead depth 3: per tile t, [wait vmcnt(8|6)] [barrier] [STAGE(t+3)] [compute(t)].
// Waves 0-3 stage 4 chunks/tile, waves 4-7 stage 3 -> per-wave vmcnt literals.
// No-max softmax (scores bounded; shift-invariant), l via ones-row of V.
__global__ __launch_bounds__(512, 2)
void attn_fwd9(const bf16* __restrict__ Qp, const bf16* __restrict__ KVp,
               bf16* __restrict__ Oout)
{
    __shared__ __align__(16) char smem[114688];   // 4 x 28672

    const int wgid = xcd_swz(blockIdx.x, gridDim.x);
    const int h  = wgid >> 4;
    const int q0 = (wgid & 15) * QBLK;
    const int tid = threadIdx.x, lane = tid & 63, w = tid >> 6;
    const int ql = lane & 31, hi = lane >> 5;
    const int q  = q0 + w * 32 + ql;

    bf16x8 qf[5];
    const bf16* qbase = Qp + ((size_t)h * SEQ + q) * DQ + hi * 8;
#pragma unroll
    for (int ks = 0; ks < 5; ++ks) qf[ks] = *(const bf16x8*)(qbase + ks * 16);

    // precomputed swizzled tile-relative LDS byte-offsets
    int aK[5], aV[4];
#pragma unroll
    for (int ks = 0; ks < 5; ++ks)
        aK[ks] = ql * 256 + (((ks * 2 + hi) ^ (ql & 15)) * 16);
#pragma unroll
    for (int u = 0; u < 4; ++u)
        aV[u] = 16384 + ql * 128 + (((u * 2 + hi) ^ (ql & 7)) * 16);

    f32x16 o[3] = {};            // O^T accum; V row 72 (ones) carries l

    const bf16* kvbase = KVp + (size_t)h * (64 * TILE_ELEMS) + (size_t)tid * 8;

    // stage tile T into buffer at byte DB: 1792 chunks; tid<256 take 4, else 3
#define STAGE(T, DB) do {                                                      \
        const bf16* s_ = kvbase + (size_t)(T) * TILE_ELEMS;                    \
        char* d_ = smem + (DB) + tid * 16;                                     \
        _Pragma("unroll")                                                      \
        for (int j_ = 0; j_ < 3; ++j_)                                         \
            gload_lds16(s_ + j_ * 4096, d_ + j_ * 8192);                       \
        if (tid < 256) gload_lds16(s_ + 12288, d_ + 24576);                    \
    } while (0)

    auto compute = [&](const char* buf) {
        // ---- S^T for both 32-key halves ----
        f32x16 sa = {}, sb = {};
        __builtin_amdgcn_s_setprio(1);
#pragma unroll
        for (int ks = 0; ks < 5; ++ks) {
            bf16x8 kf = *(const bf16x8*)(buf + aK[ks]);
            sa = __builtin_amdgcn_mfma_f32_32x32x16_bf16(kf, qf[ks], sa, 0, 0, 0);
        }
#pragma unroll
        for (int ks = 0; ks < 5; ++ks) {
            bf16x8 kf = *(const bf16x8*)(buf + 8192 + aK[ks]);
            sb = __builtin_amdgcn_mfma_f32_32x32x16_bf16(kf, qf[ks], sb, 0, 0, 0);
        }
        __builtin_amdgcn_s_setprio(0);

        // ---- P = exp2(S) directly (no-max softmax) ----
        uint32_t wd[16];
#pragma unroll
        for (int i = 0; i < 8; ++i) {
            wd[i]   = (uint32_t)bfbits(EXP2F(sa[2*i])) | ((uint32_t)bfbits(EXP2F(sa[2*i+1])) << 16);
            wd[8+i] = (uint32_t)bfbits(EXP2F(sb[2*i])) | ((uint32_t)bfbits(EXP2F(sb[2*i+1])) << 16);
        }

        // ---- P fragments: key-halves exchange via permlane32_swap ----
        PLSWAP(wd[0], wd[2]);   PLSWAP(wd[1], wd[3]);
        PLSWAP(wd[4], wd[6]);   PLSWAP(wd[5], wd[7]);
        PLSWAP(wd[8], wd[10]);  PLSWAP(wd[9], wd[11]);
        PLSWAP(wd[12], wd[14]); PLSWAP(wd[13], wd[15]);
        u32x4 u0 = {wd[0],wd[1],wd[2],wd[3]},   u1 = {wd[4],wd[5],wd[6],wd[7]};
        u32x4 u2 = {wd[8],wd[9],wd[10],wd[11]}, u3 = {wd[12],wd[13],wd[14],wd[15]};
        bf16x8 pb[4] = { __builtin_bit_cast(bf16x8, u0), __builtin_bit_cast(bf16x8, u1),
                         __builtin_bit_cast(bf16x8, u2), __builtin_bit_cast(bf16x8, u3) };

        // ---- O^T += mfma(V^T, P) ----
        __builtin_amdgcn_s_setprio(1);
#pragma unroll
        for (int db = 0; db < 3; ++db)
#pragma unroll
            for (int u = 0; u < 4; ++u) {
                bf16x8 vf = *(const bf16x8*)(buf + db * 4096 + aV[u]);
                o[db] = __builtin_amdgcn_mfma_f32_32x32x16_bf16(vf, pb[u], o[db], 0, 0, 0);
            }
        __builtin_amdgcn_s_setprio(0);
    };

#define WAIT86 do {                                                            \
        if (w < 4) asm volatile("s_waitcnt vmcnt(8)" ::: "memory");            \
        else       asm volatile("s_waitcnt vmcnt(6)" ::: "memory");            \
    } while (0)

    // prologue: stage tiles 0..2
    STAGE(0, 0); STAGE(1, 28672); STAGE(2, 57344);

    for (int tt = 0; tt < 60; tt += 4) {
#pragma unroll
        for (int j = 0; j < 4; ++j) {
            WAIT86;
            __builtin_amdgcn_s_barrier();
            STAGE(tt + j + 3, ((j + 3) & 3) * 28672);
            __builtin_amdgcn_sched_barrier(0);
            compute(smem + j * 28672);
        }
    }
    // tail: t = 60..63
    WAIT86;
    __builtin_amdgcn_s_barrier();
    STAGE(63, 86016);
    __builtin_amdgcn_sched_barrier(0);
    compute(smem);
    WAIT86;
    __builtin_amdgcn_s_barrier();
    __builtin_amdgcn_sched_barrier(0);
    compute(smem + 28672);
    if (w < 4) asm volatile("s_waitcnt vmcnt(4)" ::: "memory");
    else       asm volatile("s_waitcnt vmcnt(3)" ::: "memory");
    __builtin_amdgcn_s_barrier();
    __builtin_amdgcn_sched_barrier(0);
    compute(smem + 57344);
    asm volatile("s_waitcnt vmcnt(0)" ::: "memory");
    __builtin_amdgcn_s_barrier();
    __builtin_amdgcn_sched_barrier(0);
    compute(smem + 86016);
#undef STAGE
#undef WAIT86

    // ---- epilogue: LDS transpose (stride 82 = 41 words, odd -> conflict-free) ----
    __syncthreads();
    bf16* Os = (bf16*)smem;                        // [QBLK][82]
    {
        float lv  = o[2][4];                       // d=72 row holds l (hi=0 lanes)
        float lo_ = __shfl_xor(lv, 32);
        float invl = 1.0f / (hi ? lo_ : lv);
        int qloc = w * 32 + ql;
#pragma unroll
        for (int db = 0; db < 3; ++db)
#pragma unroll
            for (int r = 0; r < 16; ++r) {
                int dloc = (r & 3) + 8 * (r >> 2) + 4 * hi;
                int d = db * 32 + dloc;
                if (d < HD) Os[qloc * 82 + d] = (bf16)(o[db][r] * invl);
            }
    }
    __syncthreads();
    for (int i = tid; i < QBLK * 36; i += 512) {
        int row = i / 36, c = i % 36;
        uint32_t val = *(const uint32_t*)((const char*)Os + row * 164 + c * 4);
        *(uint32_t*)((char*)Oout + (size_t)(q0 + row) * 2304 + h * 144 + c * 4) = val;
    }
}

extern "C" void kernel_launch(void* const* d_in, const int* in_sizes, int n_in,
                              void* d_out, int out_size, void* d_ws, size_t ws_size,
                              hipStream_t stream)
{
    const float* hidden = (const float*)d_in[0];
    // d_in[1] = cu_seqlens: unused by the reference
    const float* cosT  = (const float*)d_in[2];
    const float* sinT  = (const float*)d_in[3];
    const float* Wqkv  = (const float*)d_in[4];
    const float* bqkv  = (const float*)d_in[5];
    const float* Wproj = (const float*)d_in[6];
    const float* bproj = (const float*)d_in[7];

    char* ws = (char*)d_ws;
    size_t off = 0;
    auto alloc = [&](size_t bytes) {
        char* p = ws + off;
        off += (bytes + 255) & ~(size_t)255;
        return p;
    };
    bf16* hid_b  = (bf16*)alloc((size_t)SEQ * HID * 2);
    bf16* WqkvT  = (bf16*)alloc((size_t)N3  * HID * 2);
    bf16* WprojT = (bf16*)alloc((size_t)HID * HID * 2);
    bf16* qkv_b  = (bf16*)alloc((size_t)SEQ * N3  * 2);
    bf16* Qp     = (bf16*)alloc((size_t)NH * SEQ * DQ * 2);
    bf16* KVp    = (bf16*)alloc((size_t)NH * 64 * TILE_ELEMS * 2);
    bf16* attno  = hid_b;  // overlay: hid_b dead after GEMM1

    prep<<<7488, 256, 0, stream>>>(hidden, Wqkv, Wproj, hid_b, WqkvT, WprojT);
    gemm_bt<0><<<dim3(SEQ / 128, N3 / 128), 256, 0, stream>>>(hid_b, WqkvT, bqkv, qkv_b,
                                                              SEQ, N3, HID);
    pack<<<33792, 256, 0, stream>>>(qkv_b, cosT, sinT, Qp, KVp);
    attn_fwd9<<<dim3(SEQ / QBLK * NH), 512, 0, stream>>>(Qp, KVp, attno);
    gemm_bt<1><<<dim3(SEQ / 128, HID / 128), 256, 0, stream>>>(attno, WprojT, bproj, d_out,
                                                               SEQ, HID, HID);
}

// Round 11
// 221.673 us; speedup vs baseline: 1.0216x; 1.0102x over previous
//
#include <hip/hip_runtime.h>
#include <hip/hip_bf16.h>
#include <stdint.h>

#define SEQ 4096
#define HID 1152
#define NH  16
#define HD  72
#define N3  3456
#define DQ  80      // Q padded head dim (5 x 16)
#define QBLK 256    // q rows per block (8 wg x 32 q; 16 waves = 8 wg x 2 kh)
#define TILE_ELEMS 14336  // 28KB tile image: K 64x256B = 16KB, V 96x128B = 12KB

typedef __bf16 bf16;
typedef __bf16 bf16x8 __attribute__((ext_vector_type(8)));
typedef float  f32x4  __attribute__((ext_vector_type(4)));
typedef float  f32x16 __attribute__((ext_vector_type(16)));
typedef uint32_t u32x4 __attribute__((ext_vector_type(4)));

#define EXP2F(x) __builtin_amdgcn_exp2f(x)
#define PLSWAP(a, b) asm("v_permlane32_swap_b32 %0, %1" : "+v"(a), "+v"(b))

__device__ __forceinline__ void gload_lds16(const void* g, void* l) {
    __builtin_amdgcn_global_load_lds(
        (__attribute__((address_space(1))) void*)(void*)g,
        (__attribute__((address_space(3))) void*)l, 16, 0, 0);
}
__device__ __forceinline__ uint16_t bfbits(float x) {
    return __builtin_bit_cast(uint16_t, (bf16)x);
}

// bijective XCD swizzle (nwg % 8 == 0 where used)
__device__ __forceinline__ int xcd_swz(int orig, int nwg) {
    return (orig & 7) * (nwg >> 3) + (orig >> 3);
}

// ---------------- fused prep: hidden f32->bf16 + both weight transposes ----------------
// blocks [0,2304): cvt hidden; [2304,6192): Wqkv^T; [6192,7488): Wproj^T
__global__ __launch_bounds__(256)
void prep(const float* __restrict__ hidden, const float* __restrict__ Wqkv,
          const float* __restrict__ Wproj, bf16* __restrict__ hid_b,
          bf16* __restrict__ WqkvT, bf16* __restrict__ WprojT)
{
    __shared__ float tl[32][33];
    int b = blockIdx.x, tid = threadIdx.x;
    if (b < 2304) {
        int i = b * 256 + tid;
        const float4* p = (const float4*)hidden + (size_t)i * 2;
        float4 a = p[0], c = p[1];
        bf16x8 o;
        o[0]=(bf16)a.x; o[1]=(bf16)a.y; o[2]=(bf16)a.z; o[3]=(bf16)a.w;
        o[4]=(bf16)c.x; o[5]=(bf16)c.y; o[6]=(bf16)c.z; o[7]=(bf16)c.w;
        ((bf16x8*)hid_b)[i] = o;
        return;
    }
    const float* in; bf16* out; int R, C, c0, r0;
    if (b < 6192) {
        int bb = b - 2304;
        in = Wqkv; out = WqkvT; R = HID; C = N3;
        c0 = (bb % 108) * 32; r0 = (bb / 108) * 32;
    } else {
        int bb = b - 6192;
        in = Wproj; out = WprojT; R = HID; C = HID;
        c0 = (bb % 36) * 32; r0 = (bb / 36) * 32;
    }
    int tx = tid & 31, ty = tid >> 5;
#pragma unroll
    for (int i = 0; i < 4; ++i)
        tl[ty + 8*i][tx] = in[(size_t)(r0 + ty + 8*i) * C + c0 + tx];
    __syncthreads();
#pragma unroll
    for (int i = 0; i < 4; ++i)
        out[(size_t)(c0 + ty + 8*i) * R + r0 + tx] = (bf16)tl[tx][ty + 8*i];
}

// ---------------- GEMM: C[M][N] = A[M][K] * BT[N][K]^T + bias ----------------
template<int OUT_F32>
__global__ __launch_bounds__(256)
void gemm_bt(const bf16* __restrict__ A, const bf16* __restrict__ BT,
             const float* __restrict__ bias, void* __restrict__ out,
             int M, int N, int K)
{
    __shared__ __align__(16) bf16 As[128 * 32];
    __shared__ __align__(16) bf16 Bs[128 * 32];
    int tid = threadIdx.x;
    int lane = tid & 63, w = tid >> 6;
    int wm = w & 1, wn = w >> 1;
    int nwg  = gridDim.x * gridDim.y;
    int wgid = xcd_swz(blockIdx.y * gridDim.x + blockIdx.x, nwg);
    int m0 = (wgid % gridDim.x) * 128, n0 = (wgid / gridDim.x) * 128;
    int lq = lane & 15, lk = lane >> 4;

    f32x4 acc[4][4] = {};

    for (int k0 = 0; k0 < K; k0 += 32) {
        __syncthreads();
#pragma unroll
        for (int i = 0; i < 2; ++i) {
            int c = w * 128 + i * 64 + lane;
            const bf16* ga = A  + (size_t)(m0 + (c >> 2)) * K + k0 + (c & 3) * 8;
            const bf16* gb = BT + (size_t)(n0 + (c >> 2)) * K + k0 + (c & 3) * 8;
            gload_lds16(ga, (char*)As + (w * 128 + i * 64) * 16);
            gload_lds16(gb, (char*)Bs + (w * 128 + i * 64) * 16);
        }
        __syncthreads();
        bf16x8 af[4], bfr[4];
#pragma unroll
        for (int m = 0; m < 4; ++m)
            af[m] = *(const bf16x8*)&As[(wm * 64 + m * 16 + lq) * 32 + lk * 8];
#pragma unroll
        for (int n = 0; n < 4; ++n)
            bfr[n] = *(const bf16x8*)&Bs[(wn * 64 + n * 16 + lq) * 32 + lk * 8];
#pragma unroll
        for (int m = 0; m < 4; ++m)
#pragma unroll
            for (int n = 0; n < 4; ++n)
                acc[m][n] = __builtin_amdgcn_mfma_f32_16x16x32_bf16(af[m], bfr[n], acc[m][n], 0, 0, 0);
    }

    int rb = m0 + wm * 64, cb = n0 + wn * 64;
#pragma unroll
    for (int m = 0; m < 4; ++m) {
#pragma unroll
        for (int n = 0; n < 4; ++n) {
            int col = cb + n * 16 + lq;
            float b = bias[col];
#pragma unroll
            for (int r = 0; r < 4; ++r) {
                int row = rb + m * 16 + lk * 4 + r;
                float v = acc[m][n][r] + b;
                if (OUT_F32) ((float*)out)[(size_t)row * N + col] = v;
                else         ((bf16*)out)[(size_t)row * N + col] = (bf16)v;
            }
        }
    }
}

// ---------------- fused pack: RoPE Q/K + V-transpose into KVp tile images ----------------
// blocks [0,32768): rope; [32768,33792): V pack.
// KVp[h][t][14336]: 0..8191 K image (chunk = key*16 + (dchunk^(key&15)));
// 8192..14335 V image (chunk d*8+cpos holds keys (cpos^(d&7))*8.. at dim d;
// d 0..71 data, 72 ones (l via MFMA), 73..95 zero).
__global__ __launch_bounds__(256)
void pack(const bf16* __restrict__ qkv, const float* __restrict__ cs,
          const float* __restrict__ sn, bf16* __restrict__ Qp,
          bf16* __restrict__ KVp)
{
    __shared__ __align__(16) bf16 tl[64][80];
    int b = blockIdx.x, tid = threadIdx.x;
    if (b < 32768) {
        int idx = b * 256 + tid;                 // NH*SEQ*128
        int dd = idx & 127;
        int s  = (idx >> 7) & (SEQ - 1);
        int h  = idx >> 19;
        float qv = 0.f, kv = 0.f;
        if (dd < HD) {
            const bf16* row = qkv + (size_t)s * N3 + h * HD;
            float c  = cs[s * HD + dd], si = sn[s * HD + dd];
            int   dp = (dd < 36) ? dd + 36 : dd - 36;
            float sg = (dd < 36) ? -1.f : 1.f;
            float qa = (float)row[dd],       qb = (float)row[dp];
            float ka = (float)row[HID + dd], kb = (float)row[HID + dp];
            qv = (qa * c + sg * qb * si) * (0.11785113019775793f * 1.4426950408889634f);
            kv =  ka * c + sg * kb * si;
        }
        int t = s >> 6, key = s & 63;
        int chunk = key * 16 + ((dd >> 3) ^ (key & 15));
        KVp[((size_t)(h * 64 + t)) * TILE_ELEMS + chunk * 8 + (dd & 7)] = (bf16)kv;
        if (dd < DQ) Qp[((size_t)h * SEQ + s) * DQ + dd] = (bf16)qv;
        return;
    }
    int bb = b - 32768;
    int t = bb & 63, h = bb >> 6, s0 = t * 64;
    for (int i = tid; i < 64 * 9; i += 256) {
        int key = i / 9, c8 = (i % 9) * 8;
        *(bf16x8*)&tl[key][c8] =
            *(const bf16x8*)&qkv[(size_t)(s0 + key) * N3 + 2 * HID + h * HD + c8];
    }
    __syncthreads();
    bf16* dst = KVp + ((size_t)(h * 64 + t)) * TILE_ELEMS + 8192;
    for (int vcid = tid; vcid < 768; vcid += 256) {     // 96 rows x 8 chunks
        int d = vcid >> 3, cpos = vcid & 7;
        int kb8 = (cpos ^ (d & 7)) << 3;
        bf16x8 v;
#pragma unroll
        for (int j = 0; j < 8; ++j)
            v[j] = (d < HD) ? tl[kb8 + j][d] : ((d == HD) ? (bf16)1.f : (bf16)0.f);
        *(bf16x8*)&dst[vcid * 8] = v;
    }
}

// ---- flash attention: 16 waves (8 q-subtiles x 2 K-halves), 4 waves/SIMD ----
// TLP-doubling round: same 32q-wave body as attn_fwd7, but 16 waves/block so
// each SIMD holds 4 waves -> softmax-VALU of some waves overlaps MFMA of others.
// K-split kh=0/1 over even/odd 64-key tiles; no-max softmax makes the partial
// (O,l) directly additive (pure LDS add merge). Pair-of-tiles double buffer at
// bytes 0 / 65536 (XOR flip on precomputed address registers).
__global__ __launch_bounds__(1024, 4)
void attn_fwd10(const bf16* __restrict__ Qp, const bf16* __restrict__ KVp,
                bf16* __restrict__ Oout)
{
    __shared__ __align__(16) char smem[122880];

    const int wgid = xcd_swz(blockIdx.x, gridDim.x);
    const int h  = wgid >> 4;
    const int q0 = (wgid & 15) * QBLK;
    const int tid = threadIdx.x, lane = tid & 63, w = tid >> 6;
    const int wg = w & 7, kh = w >> 3;
    const int ql = lane & 31, hi = lane >> 5;
    const int q  = q0 + wg * 32 + ql;

    // Q fragments (B-operand): Qf[ks][j] = Q[q][ks*16 + hi*8 + j]
    bf16x8 qf[5];
    const bf16* qbase = Qp + ((size_t)h * SEQ + q) * DQ + hi * 8;
#pragma unroll
    for (int ks = 0; ks < 5; ++ks) qf[ks] = *(const bf16x8*)(qbase + ks * 16);

    // precomputed swizzled LDS byte-offsets (kh picks the tile half; bit16 = buffer)
    int aK[5], aV[4];
#pragma unroll
    for (int ks = 0; ks < 5; ++ks)
        aK[ks] = kh * 28672 + ql * 256 + (((ks * 2 + hi) ^ (ql & 15)) * 16);
#pragma unroll
    for (int u = 0; u < 4; ++u)
        aV[u] = kh * 28672 + 16384 + ql * 128 + (((u * 2 + hi) ^ (ql & 7)) * 16);

    f32x16 o[3] = {};            // O^T accum; V row 72 (ones) carries l

    const bf16* kvsrc = KVp + (size_t)h * (64 * TILE_ELEMS) + (size_t)tid * 8;

    // stage pair P (tiles 2P,2P+1 = 56KB) into buffer at byte BASE; 3584 chunks,
    // 1024 threads: tid<512 take 4 chunks, others 3
#define STAGE(P, BASE) do {                                                    \
        const bf16* s_ = kvsrc + (size_t)(P) * 28672;                          \
        char* d_ = smem + (BASE) + tid * 16;                                   \
        _Pragma("unroll")                                                      \
        for (int j_ = 0; j_ < 3; ++j_)                                         \
            gload_lds16(s_ + j_ * 8192, d_ + j_ * 16384);                      \
        if (tid < 512) gload_lds16(s_ + 24576, d_ + 49152);                    \
    } while (0)

    STAGE(0, 0);
    int stageBase = 65536;
    asm volatile("s_waitcnt vmcnt(0)" ::: "memory");
    __builtin_amdgcn_s_barrier();

    for (int t = 0; t < 32; ++t) {
        __builtin_amdgcn_sched_barrier(0);
        if (t + 1 < 32) STAGE(t + 1, stageBase);

        // ---- S^T for both 32-key halves of my tile ----
        f32x16 sa = {}, sb = {};
        __builtin_amdgcn_s_setprio(1);
#pragma unroll
        for (int ks = 0; ks < 5; ++ks) {
            bf16x8 kf = *(const bf16x8*)(smem + aK[ks]);
            sa = __builtin_amdgcn_mfma_f32_32x32x16_bf16(kf, qf[ks], sa, 0, 0, 0);
        }
#pragma unroll
        for (int ks = 0; ks < 5; ++ks) {
            bf16x8 kf = *(const bf16x8*)(smem + aK[ks] + 8192);
            sb = __builtin_amdgcn_mfma_f32_32x32x16_bf16(kf, qf[ks], sb, 0, 0, 0);
        }
        __builtin_amdgcn_s_setprio(0);

        // ---- P = exp2(S) directly (no-max softmax; scores bounded) ----
        uint32_t wd[16];
#pragma unroll
        for (int i = 0; i < 8; ++i) {
            wd[i]   = (uint32_t)bfbits(EXP2F(sa[2*i])) | ((uint32_t)bfbits(EXP2F(sa[2*i+1])) << 16);
            wd[8+i] = (uint32_t)bfbits(EXP2F(sb[2*i])) | ((uint32_t)bfbits(EXP2F(sb[2*i+1])) << 16);
        }

        // ---- P fragments: key-halves exchange via permlane32_swap ----
        PLSWAP(wd[0], wd[2]);   PLSWAP(wd[1], wd[3]);
        PLSWAP(wd[4], wd[6]);   PLSWAP(wd[5], wd[7]);
        PLSWAP(wd[8], wd[10]);  PLSWAP(wd[9], wd[11]);
        PLSWAP(wd[12], wd[14]); PLSWAP(wd[13], wd[15]);
        u32x4 u0 = {wd[0],wd[1],wd[2],wd[3]},   u1 = {wd[4],wd[5],wd[6],wd[7]};
        u32x4 u2 = {wd[8],wd[9],wd[10],wd[11]}, u3 = {wd[12],wd[13],wd[14],wd[15]};
        bf16x8 pb[4] = { __builtin_bit_cast(bf16x8, u0), __builtin_bit_cast(bf16x8, u1),
                         __builtin_bit_cast(bf16x8, u2), __builtin_bit_cast(bf16x8, u3) };

        // ---- O^T += mfma(V^T, P)  (V row 72 = ones -> accumulates l) ----
        __builtin_amdgcn_s_setprio(1);
#pragma unroll
        for (int db = 0; db < 3; ++db)
#pragma unroll
            for (int u = 0; u < 4; ++u) {
                bf16x8 vf = *(const bf16x8*)(smem + aV[u] + db * 4096);
                o[db] = __builtin_amdgcn_mfma_f32_32x32x16_bf16(vf, pb[u], o[db], 0, 0, 0);
            }
        __builtin_amdgcn_s_setprio(0);

        __builtin_amdgcn_sched_barrier(0);
        asm volatile("s_waitcnt vmcnt(0)" ::: "memory");   // own staged loads landed
        __builtin_amdgcn_s_barrier();                      // current pair consumed
#pragma unroll
        for (int ks = 0; ks < 5; ++ks) aK[ks] ^= 65536;
#pragma unroll
        for (int u = 0; u < 4; ++u)    aV[u] ^= 65536;
        stageBase ^= 65536;
    }
#undef STAGE

    // ---- K-split merge: kh=1 partials added into kh=0 (pure add, no rescale) ----
    __syncthreads();
    float* M = (float*)smem;                      // [8 slots][64 lanes] stride 49
    const int slot = (wg * 64 + lane) * 49;
    if (kh == 1) {
#pragma unroll
        for (int db = 0; db < 3; ++db)
#pragma unroll
            for (int r = 0; r < 16; ++r)
                M[slot + db * 16 + r] = o[db][r];
    }
    __syncthreads();
    if (kh == 0) {
#pragma unroll
        for (int db = 0; db < 3; ++db)
#pragma unroll
            for (int r = 0; r < 16; ++r)
                o[db][r] += M[slot + db * 16 + r];
    }
    __syncthreads();

    // ---- epilogue: LDS transpose (stride 82 = 41 words, odd -> conflict-free) ----
    bf16* Os = (bf16*)smem;                        // [QBLK][82]
    if (kh == 0) {
        float lv  = o[2][4];                       // d=72 row holds l (hi=0 lanes)
        float lo_ = __shfl_xor(lv, 32);
        float invl = 1.0f / (hi ? lo_ : lv);
        int qloc = wg * 32 + ql;
#pragma unroll
        for (int db = 0; db < 3; ++db)
#pragma unroll
            for (int r = 0; r < 16; ++r) {
                int dloc = (r & 3) + 8 * (r >> 2) + 4 * hi;
                int d = db * 32 + dloc;
                if (d < HD) Os[qloc * 82 + d] = (bf16)(o[db][r] * invl);
            }
    }
    __syncthreads();
    for (int i = tid; i < QBLK * 36; i += 1024) {
        int row = i / 36, c = i % 36;
        uint32_t val = *(const uint32_t*)((const char*)Os + row * 164 + c * 4);
        *(uint32_t*)((char*)Oout + (size_t)(q0 + row) * 2304 + h * 144 + c * 4) = val;
    }
}

extern "C" void kernel_launch(void* const* d_in, const int* in_sizes, int n_in,
                              void* d_out, int out_size, void* d_ws, size_t ws_size,
                              hipStream_t stream)
{
    const float* hidden = (const float*)d_in[0];
    // d_in[1] = cu_seqlens: unused by the reference
    const float* cosT  = (const float*)d_in[2];
    const float* sinT  = (const float*)d_in[3];
    const float* Wqkv  = (const float*)d_in[4];
    const float* bqkv  = (const float*)d_in[5];
    const float* Wproj = (const float*)d_in[6];
    const float* bproj = (const float*)d_in[7];

    char* ws = (char*)d_ws;
    size_t off = 0;
    auto alloc = [&](size_t bytes) {
        char* p = ws + off;
        off += (bytes + 255) & ~(size_t)255;
        return p;
    };
    bf16* hid_b  = (bf16*)alloc((size_t)SEQ * HID * 2);
    bf16* WqkvT  = (bf16*)alloc((size_t)N3  * HID * 2);
    bf16* WprojT = (bf16*)alloc((size_t)HID * HID * 2);
    bf16* qkv_b  = (bf16*)alloc((size_t)SEQ * N3  * 2);
    bf16* Qp     = (bf16*)alloc((size_t)NH * SEQ * DQ * 2);
    bf16* KVp    = (bf16*)alloc((size_t)NH * 64 * TILE_ELEMS * 2);
    bf16* attno  = hid_b;  // overlay: hid_b dead after GEMM1

    prep<<<7488, 256, 0, stream>>>(hidden, Wqkv, Wproj, hid_b, WqkvT, WprojT);
    gemm_bt<0><<<dim3(SEQ / 128, N3 / 128), 256, 0, stream>>>(hid_b, WqkvT, bqkv, qkv_b,
                                                              SEQ, N3, HID);
    pack<<<33792, 256, 0, stream>>>(qkv_b, cosT, sinT, Qp, KVp);
    attn_fwd10<<<dim3(SEQ / QBLK * NH), 1024, 0, stream>>>(Qp, KVp, attno);
    gemm_bt<1><<<dim3(SEQ / 128, HID / 128), 256, 0, stream>>>(attno, WprojT, bproj, d_out,
                                                               SEQ, HID, HID);
}

// Round 12
// 221.487 us; speedup vs baseline: 1.0224x; 1.0008x over previous
//
#include <hip/hip_runtime.h>
#include <hip/hip_bf16.h>
#include <stdint.h>

#define SEQ 4096
#define HID 1152
#define NH  16
#define HD  72
#define N3  3456
#define DQ  80      // Q padded head dim (5 x 16)
#define QBLK 256    // q rows per block (8 waves x 32)
#define TILE_ELEMS 14336  // 28KB tile image: K 64x256B = 16KB, V 96x128B = 12KB

typedef __bf16 bf16;
typedef __bf16 bf16x8 __attribute__((ext_vector_type(8)));
typedef float  f32x4  __attribute__((ext_vector_type(4)));
typedef float  f32x16 __attribute__((ext_vector_type(16)));
typedef uint32_t u32x4 __attribute__((ext_vector_type(4)));

#define EXP2F(x) __builtin_amdgcn_exp2f(x)
#define PLSWAP(a, b) asm("v_permlane32_swap_b32 %0, %1" : "+v"(a), "+v"(b))

__device__ __forceinline__ void gload_lds16(const void* g, void* l) {
    __builtin_amdgcn_global_load_lds(
        (__attribute__((address_space(1))) void*)(void*)g,
        (__attribute__((address_space(3))) void*)l, 16, 0, 0);
}
__device__ __forceinline__ uint16_t bfbits(float x) {
    return __builtin_bit_cast(uint16_t, (bf16)x);
}

// bijective XCD swizzle (nwg % 8 == 0 where used)
__device__ __forceinline__ int xcd_swz(int orig, int nwg) {
    return (orig & 7) * (nwg >> 3) + (orig >> 3);
}

// ---------------- fused prep: hidden f32->bf16 + both weight transposes ----------------
// blocks [0,2304): cvt hidden; [2304,6192): Wqkv^T; [6192,7488): Wproj^T
__global__ __launch_bounds__(256)
void prep(const float* __restrict__ hidden, const float* __restrict__ Wqkv,
          const float* __restrict__ Wproj, bf16* __restrict__ hid_b,
          bf16* __restrict__ WqkvT, bf16* __restrict__ WprojT)
{
    __shared__ float tl[32][33];
    int b = blockIdx.x, tid = threadIdx.x;
    if (b < 2304) {
        int i = b * 256 + tid;
        const float4* p = (const float4*)hidden + (size_t)i * 2;
        float4 a = p[0], c = p[1];
        bf16x8 o;
        o[0]=(bf16)a.x; o[1]=(bf16)a.y; o[2]=(bf16)a.z; o[3]=(bf16)a.w;
        o[4]=(bf16)c.x; o[5]=(bf16)c.y; o[6]=(bf16)c.z; o[7]=(bf16)c.w;
        ((bf16x8*)hid_b)[i] = o;
        return;
    }
    const float* in; bf16* out; int R, C, c0, r0;
    if (b < 6192) {
        int bb = b - 2304;
        in = Wqkv; out = WqkvT; R = HID; C = N3;
        c0 = (bb % 108) * 32; r0 = (bb / 108) * 32;
    } else {
        int bb = b - 6192;
        in = Wproj; out = WprojT; R = HID; C = HID;
        c0 = (bb % 36) * 32; r0 = (bb / 36) * 32;
    }
    int tx = tid & 31, ty = tid >> 5;
#pragma unroll
    for (int i = 0; i < 4; ++i)
        tl[ty + 8*i][tx] = in[(size_t)(r0 + ty + 8*i) * C + c0 + tx];
    __syncthreads();
#pragma unroll
    for (int i = 0; i < 4; ++i)
        out[(size_t)(c0 + ty + 8*i) * R + r0 + tx] = (bf16)tl[tx][ty + 8*i];
}

// ---------------- GEMM: C[M][N] = A[M][K] * BT[N][K]^T + bias ----------------
template<int OUT_F32>
__global__ __launch_bounds__(256)
void gemm_bt(const bf16* __restrict__ A, const bf16* __restrict__ BT,
             const float* __restrict__ bias, void* __restrict__ out,
             int M, int N, int K)
{
    __shared__ __align__(16) bf16 As[128 * 32];
    __shared__ __align__(16) bf16 Bs[128 * 32];
    int tid = threadIdx.x;
    int lane = tid & 63, w = tid >> 6;
    int wm = w & 1, wn = w >> 1;
    int nwg  = gridDim.x * gridDim.y;
    int wgid = xcd_swz(blockIdx.y * gridDim.x + blockIdx.x, nwg);
    int m0 = (wgid % gridDim.x) * 128, n0 = (wgid / gridDim.x) * 128;
    int lq = lane & 15, lk = lane >> 4;

    f32x4 acc[4][4] = {};

    for (int k0 = 0; k0 < K; k0 += 32) {
        __syncthreads();
#pragma unroll
        for (int i = 0; i < 2; ++i) {
            int c = w * 128 + i * 64 + lane;
            const bf16* ga = A  + (size_t)(m0 + (c >> 2)) * K + k0 + (c & 3) * 8;
            const bf16* gb = BT + (size_t)(n0 + (c >> 2)) * K + k0 + (c & 3) * 8;
            gload_lds16(ga, (char*)As + (w * 128 + i * 64) * 16);
            gload_lds16(gb, (char*)Bs + (w * 128 + i * 64) * 16);
        }
        __syncthreads();
        bf16x8 af[4], bfr[4];
#pragma unroll
        for (int m = 0; m < 4; ++m)
            af[m] = *(const bf16x8*)&As[(wm * 64 + m * 16 + lq) * 32 + lk * 8];
#pragma unroll
        for (int n = 0; n < 4; ++n)
            bfr[n] = *(const bf16x8*)&Bs[(wn * 64 + n * 16 + lq) * 32 + lk * 8];
#pragma unroll
        for (int m = 0; m < 4; ++m)
#pragma unroll
            for (int n = 0; n < 4; ++n)
                acc[m][n] = __builtin_amdgcn_mfma_f32_16x16x32_bf16(af[m], bfr[n], acc[m][n], 0, 0, 0);
    }

    int rb = m0 + wm * 64, cb = n0 + wn * 64;
#pragma unroll
    for (int m = 0; m < 4; ++m) {
#pragma unroll
        for (int n = 0; n < 4; ++n) {
            int col = cb + n * 16 + lq;
            float b = bias[col];
#pragma unroll
            for (int r = 0; r < 4; ++r) {
                int row = rb + m * 16 + lk * 4 + r;
                float v = acc[m][n][r] + b;
                if (OUT_F32) ((float*)out)[(size_t)row * N + col] = v;
                else         ((bf16*)out)[(size_t)row * N + col] = (bf16)v;
            }
        }
    }
}

// ---------------- fused pack: RoPE Q/K + V-transpose into KVp tile images ----------------
// blocks [0,32768): rope; [32768,33792): V pack.
// KVp[h][t][14336]: 0..8191 K image (chunk = key*16 + (dchunk^(key&15)));
// 8192..14335 V image (chunk d*8+cpos holds keys (cpos^(d&7))*8.. at dim d;
// d 0..71 data, 72 ones (l via MFMA), 73..95 zero).
__global__ __launch_bounds__(256)
void pack(const bf16* __restrict__ qkv, const float* __restrict__ cs,
          const float* __restrict__ sn, bf16* __restrict__ Qp,
          bf16* __restrict__ KVp)
{
    __shared__ __align__(16) bf16 tl[64][80];
    int b = blockIdx.x, tid = threadIdx.x;
    if (b < 32768) {
        int idx = b * 256 + tid;                 // NH*SEQ*128
        int dd = idx & 127;
        int s  = (idx >> 7) & (SEQ - 1);
        int h  = idx >> 19;
        float qv = 0.f, kv = 0.f;
        if (dd < HD) {
            const bf16* row = qkv + (size_t)s * N3 + h * HD;
            float c  = cs[s * HD + dd], si = sn[s * HD + dd];
            int   dp = (dd < 36) ? dd + 36 : dd - 36;
            float sg = (dd < 36) ? -1.f : 1.f;
            float qa = (float)row[dd],       qb = (float)row[dp];
            float ka = (float)row[HID + dd], kb = (float)row[HID + dp];
            qv = (qa * c + sg * qb * si) * (0.11785113019775793f * 1.4426950408889634f);
            kv =  ka * c + sg * kb * si;
        }
        int t = s >> 6, key = s & 63;
        int chunk = key * 16 + ((dd >> 3) ^ (key & 15));
        KVp[((size_t)(h * 64 + t)) * TILE_ELEMS + chunk * 8 + (dd & 7)] = (bf16)kv;
        if (dd < DQ) Qp[((size_t)h * SEQ + s) * DQ + dd] = (bf16)qv;
        return;
    }
    int bb = b - 32768;
    int t = bb & 63, h = bb >> 6, s0 = t * 64;
    for (int i = tid; i < 64 * 9; i += 256) {
        int key = i / 9, c8 = (i % 9) * 8;
        *(bf16x8*)&tl[key][c8] =
            *(const bf16x8*)&qkv[(size_t)(s0 + key) * N3 + 2 * HID + h * HD + c8];
    }
    __syncthreads();
    bf16* dst = KVp + ((size_t)(h * 64 + t)) * TILE_ELEMS + 8192;
    for (int vcid = tid; vcid < 768; vcid += 256) {     // 96 rows x 8 chunks
        int d = vcid >> 3, cpos = vcid & 7;
        int kb8 = (cpos ^ (d & 7)) << 3;
        bf16x8 v;
#pragma unroll
        for (int j = 0; j < 8; ++j)
            v[j] = (d < HD) ? tl[kb8 + j][d] : ((d == HD) ? (bf16)1.f : (bf16)0.f);
        *(bf16x8*)&dst[vcid * 8] = v;
    }
}

// ---- flash attention: 8 waves x 32q, 3-buffer rotation, T15 within-wave pipeline ----
// Iteration t: STAGE(t+1) -> buf[(t+1)%3]; QK(t) from buf[t%3] (scores held to t+1);
// exp/pack(t-1) on VALU + PV(t-1) from buf[(t-1)%3]. The exp chain of tile t-1 thus
// overlaps the QK MFMAs of tile t inside the same wave -- breaking the serial
// QK->exp->PV chain that left ~19% of cycles idle in R8-R11. No-max softmax
// (scores bounded, shift-invariant); l via ones-row of V through the PV MFMA.
__global__ __launch_bounds__(512, 2)
void attn_fwd11(const bf16* __restrict__ Qp, const bf16* __restrict__ KVp,
                bf16* __restrict__ Oout)
{
    __shared__ __align__(16) char smem[86016];   // 3 x 28672

    const int wgid = xcd_swz(blockIdx.x, gridDim.x);
    const int h  = wgid >> 4;
    const int q0 = (wgid & 15) * QBLK;
    const int tid = threadIdx.x, lane = tid & 63, w = tid >> 6;
    const int ql = lane & 31, hi = lane >> 5;
    const int q  = q0 + w * 32 + ql;

    // Q fragments (B-operand): Qf[ks][j] = Q[q][ks*16 + hi*8 + j]
    bf16x8 qf[5];
    const bf16* qbase = Qp + ((size_t)h * SEQ + q) * DQ + hi * 8;
#pragma unroll
    for (int ks = 0; ks < 5; ++ks) qf[ks] = *(const bf16x8*)(qbase + ks * 16);

    // precomputed swizzled tile-relative LDS byte-offsets
    int aK[5], aV[4];
#pragma unroll
    for (int ks = 0; ks < 5; ++ks)
        aK[ks] = ql * 256 + (((ks * 2 + hi) ^ (ql & 15)) * 16);
#pragma unroll
    for (int u = 0; u < 4; ++u)
        aV[u] = 16384 + ql * 128 + (((u * 2 + hi) ^ (ql & 7)) * 16);

    f32x16 o[3] = {};            // O^T accum; V row 72 (ones) carries l

    const bf16* kvbase = KVp + (size_t)h * (64 * TILE_ELEMS) + (size_t)tid * 8;

    // stage tile T into buffer at byte DB: 1792 x 16B chunks; tid<256 take 4, else 3
#define STAGE(T, DB) do {                                                      \
        const bf16* s_ = kvbase + (size_t)(T) * TILE_ELEMS;                    \
        char* d_ = smem + (DB) + tid * 16;                                     \
        _Pragma("unroll")                                                      \
        for (int j_ = 0; j_ < 3; ++j_)                                         \
            gload_lds16(s_ + j_ * 4096, d_ + j_ * 8192);                       \
        if (tid < 256) gload_lds16(s_ + 12288, d_ + 24576);                    \
    } while (0)

    // QK^T of one tile: scores for both 32-key halves (held in registers)
    auto qk = [&](const char* bK, f32x16& sa, f32x16& sb) {
        __builtin_amdgcn_s_setprio(1);
#pragma unroll
        for (int ks = 0; ks < 5; ++ks) {
            bf16x8 kf = *(const bf16x8*)(bK + aK[ks]);
            sa = __builtin_amdgcn_mfma_f32_32x32x16_bf16(kf, qf[ks], sa, 0, 0, 0);
        }
#pragma unroll
        for (int ks = 0; ks < 5; ++ks) {
            bf16x8 kf = *(const bf16x8*)(bK + 8192 + aK[ks]);
            sb = __builtin_amdgcn_mfma_f32_32x32x16_bf16(kf, qf[ks], sb, 0, 0, 0);
        }
        __builtin_amdgcn_s_setprio(0);
    };

    // exp + pack + PV of the previous tile (V in buffer bV)
    auto expv = [&](const f32x16& sa, const f32x16& sb, const char* bV) {
        uint32_t wd[16];
#pragma unroll
        for (int i = 0; i < 8; ++i) {
            wd[i]   = (uint32_t)bfbits(EXP2F(sa[2*i])) | ((uint32_t)bfbits(EXP2F(sa[2*i+1])) << 16);
            wd[8+i] = (uint32_t)bfbits(EXP2F(sb[2*i])) | ((uint32_t)bfbits(EXP2F(sb[2*i+1])) << 16);
        }
        PLSWAP(wd[0], wd[2]);   PLSWAP(wd[1], wd[3]);
        PLSWAP(wd[4], wd[6]);   PLSWAP(wd[5], wd[7]);
        PLSWAP(wd[8], wd[10]);  PLSWAP(wd[9], wd[11]);
        PLSWAP(wd[12], wd[14]); PLSWAP(wd[13], wd[15]);
        u32x4 u0 = {wd[0],wd[1],wd[2],wd[3]},   u1 = {wd[4],wd[5],wd[6],wd[7]};
        u32x4 u2 = {wd[8],wd[9],wd[10],wd[11]}, u3 = {wd[12],wd[13],wd[14],wd[15]};
        bf16x8 pb[4] = { __builtin_bit_cast(bf16x8, u0), __builtin_bit_cast(bf16x8, u1),
                         __builtin_bit_cast(bf16x8, u2), __builtin_bit_cast(bf16x8, u3) };
        __builtin_amdgcn_s_setprio(1);
#pragma unroll
        for (int db = 0; db < 3; ++db)
#pragma unroll
            for (int u = 0; u < 4; ++u) {
                bf16x8 vf = *(const bf16x8*)(bV + db * 4096 + aV[u]);
                o[db] = __builtin_amdgcn_mfma_f32_32x32x16_bf16(vf, pb[u], o[db], 0, 0, 0);
            }
        __builtin_amdgcn_s_setprio(0);
    };

    f32x16 pa = {}, pb_ = {};    // previous tile's scores (pipeline state)

    // prologue: tile 0 staged+computed; tile 1 staged
    STAGE(0, 0);
    asm volatile("s_waitcnt vmcnt(0)" ::: "memory");
    __builtin_amdgcn_s_barrier();
    STAGE(1, 28672);
    qk(smem, pa, pb_);
    asm volatile("s_waitcnt vmcnt(0)" ::: "memory");
    __builtin_amdgcn_s_barrier();

#define BODY(T, KB, VB, SB) do {                                               \
        if ((T) < 63) STAGE((T) + 1, SB);                                      \
        f32x16 ca = {}, cb = {};                                               \
        qk(smem + (KB), ca, cb);                                               \
        expv(pa, pb_, smem + (VB));                                            \
        pa = ca; pb_ = cb;                                                     \
        __builtin_amdgcn_sched_barrier(0);                                     \
        asm volatile("s_waitcnt vmcnt(0)" ::: "memory");                       \
        __builtin_amdgcn_s_barrier();                                          \
    } while (0)

    for (int t = 1; t < 64; t += 3) {
        BODY(t,     28672, 0,     57344);
        BODY(t + 1, 57344, 28672, 0);
        BODY(t + 2, 0,     57344, 28672);
    }
    // drain pipeline: exp/PV of tile 63 (V resident in buffer 0)
    expv(pa, pb_, smem);
#undef BODY
#undef STAGE

    // ---- epilogue: LDS transpose (stride 82 = 41 words, odd -> conflict-free) ----
    __syncthreads();
    bf16* Os = (bf16*)smem;                        // [QBLK][82]
    {
        float lv  = o[2][4];                       // d=72 row holds l (hi=0 lanes)
        float lo_ = __shfl_xor(lv, 32);
        float invl = 1.0f / (hi ? lo_ : lv);
        int qloc = w * 32 + ql;
#pragma unroll
        for (int db = 0; db < 3; ++db)
#pragma unroll
            for (int r = 0; r < 16; ++r) {
                int dloc = (r & 3) + 8 * (r >> 2) + 4 * hi;
                int d = db * 32 + dloc;
                if (d < HD) Os[qloc * 82 + d] = (bf16)(o[db][r] * invl);
            }
    }
    __syncthreads();
    for (int i = tid; i < QBLK * 36; i += 512) {
        int row = i / 36, c = i % 36;
        uint32_t val = *(const uint32_t*)((const char*)Os + row * 164 + c * 4);
        *(uint32_t*)((char*)Oout + (size_t)(q0 + row) * 2304 + h * 144 + c * 4) = val;
    }
}

extern "C" void kernel_launch(void* const* d_in, const int* in_sizes, int n_in,
                              void* d_out, int out_size, void* d_ws, size_t ws_size,
                              hipStream_t stream)
{
    const float* hidden = (const float*)d_in[0];
    // d_in[1] = cu_seqlens: unused by the reference
    const float* cosT  = (const float*)d_in[2];
    const float* sinT  = (const float*)d_in[3];
    const float* Wqkv  = (const float*)d_in[4];
    const float* bqkv  = (const float*)d_in[5];
    const float* Wproj = (const float*)d_in[6];
    const float* bproj = (const float*)d_in[7];

    char* ws = (char*)d_ws;
    size_t off = 0;
    auto alloc = [&](size_t bytes) {
        char* p = ws + off;
        off += (bytes + 255) & ~(size_t)255;
        return p;
    };
    bf16* hid_b  = (bf16*)alloc((size_t)SEQ * HID * 2);
    bf16* WqkvT  = (bf16*)alloc((size_t)N3  * HID * 2);
    bf16* WprojT = (bf16*)alloc((size_t)HID * HID * 2);
    bf16* qkv_b  = (bf16*)alloc((size_t)SEQ * N3  * 2);
    bf16* Qp     = (bf16*)alloc((size_t)NH * SEQ * DQ * 2);
    bf16* KVp    = (bf16*)alloc((size_t)NH * 64 * TILE_ELEMS * 2);
    bf16* attno  = hid_b;  // overlay: hid_b dead after GEMM1

    prep<<<7488, 256, 0, stream>>>(hidden, Wqkv, Wproj, hid_b, WqkvT, WprojT);
    gemm_bt<0><<<dim3(SEQ / 128, N3 / 128), 256, 0, stream>>>(hid_b, WqkvT, bqkv, qkv_b,
                                                              SEQ, N3, HID);
    pack<<<33792, 256, 0, stream>>>(qkv_b, cosT, sinT, Qp, KVp);
    attn_fwd11<<<dim3(SEQ / QBLK * NH), 512, 0, stream>>>(Qp, KVp, attno);
    gemm_bt<1><<<dim3(SEQ / 128, HID / 128), 256, 0, stream>>>(attno, WprojT, bproj, d_out,
                                                               SEQ, HID, HID);
}

// Round 13
// 205.078 us; speedup vs baseline: 1.1042x; 1.0800x over previous
//
#include <hip/hip_runtime.h>
#include <hip/hip_bf16.h>
#include <stdint.h>

#define SEQ 4096
#define HID 1152
#define NH  16
#define HD  72
#define N3  3456
#define DQ  80      // Q padded head dim (5 x 16)
#define QBLK 256    // q rows per block (8 waves x 32)
#define TILE_ELEMS 14336  // 28KB tile image: K 64x256B = 16KB, V 96x128B = 12KB

typedef __bf16 bf16;
typedef __bf16 bf16x8 __attribute__((ext_vector_type(8)));
typedef float  f32x4  __attribute__((ext_vector_type(4)));
typedef float  f32x16 __attribute__((ext_vector_type(16)));
typedef uint32_t u32x4 __attribute__((ext_vector_type(4)));

#define EXP2F(x) __builtin_amdgcn_exp2f(x)
#define PLSWAP(a, b) asm("v_permlane32_swap_b32 %0, %1" : "+v"(a), "+v"(b))

__device__ __forceinline__ void gload_lds16(const void* g, void* l) {
    __builtin_amdgcn_global_load_lds(
        (__attribute__((address_space(1))) void*)(void*)g,
        (__attribute__((address_space(3))) void*)l, 16, 0, 0);
}
__device__ __forceinline__ uint16_t bfbits(float x) {
    return __builtin_bit_cast(uint16_t, (bf16)x);
}

// bijective XCD swizzle (nwg % 8 == 0 where used)
__device__ __forceinline__ int xcd_swz(int orig, int nwg) {
    return (orig & 7) * (nwg >> 3) + (orig >> 3);
}

// ---------------- fused prep: hidden f32->bf16 + both weight transposes ----------------
// blocks [0,2304): cvt hidden; [2304,6192): Wqkv^T; [6192,7488): Wproj^T
__global__ __launch_bounds__(256)
void prep(const float* __restrict__ hidden, const float* __restrict__ Wqkv,
          const float* __restrict__ Wproj, bf16* __restrict__ hid_b,
          bf16* __restrict__ WqkvT, bf16* __restrict__ WprojT)
{
    __shared__ float tl[32][33];
    int b = blockIdx.x, tid = threadIdx.x;
    if (b < 2304) {
        int i = b * 256 + tid;
        const float4* p = (const float4*)hidden + (size_t)i * 2;
        float4 a = p[0], c = p[1];
        bf16x8 o;
        o[0]=(bf16)a.x; o[1]=(bf16)a.y; o[2]=(bf16)a.z; o[3]=(bf16)a.w;
        o[4]=(bf16)c.x; o[5]=(bf16)c.y; o[6]=(bf16)c.z; o[7]=(bf16)c.w;
        ((bf16x8*)hid_b)[i] = o;
        return;
    }
    const float* in; bf16* out; int R, C, c0, r0;
    if (b < 6192) {
        int bb = b - 2304;
        in = Wqkv; out = WqkvT; R = HID; C = N3;
        c0 = (bb % 108) * 32; r0 = (bb / 108) * 32;
    } else {
        int bb = b - 6192;
        in = Wproj; out = WprojT; R = HID; C = HID;
        c0 = (bb % 36) * 32; r0 = (bb / 36) * 32;
    }
    int tx = tid & 31, ty = tid >> 5;
#pragma unroll
    for (int i = 0; i < 4; ++i)
        tl[ty + 8*i][tx] = in[(size_t)(r0 + ty + 8*i) * C + c0 + tx];
    __syncthreads();
#pragma unroll
    for (int i = 0; i < 4; ++i)
        out[(size_t)(c0 + ty + 8*i) * R + r0 + tx] = (bf16)tl[tx][ty + 8*i];
}

// ---------------- GEMM: C[M][N] = A[M][K] * BT[N][K]^T + bias ----------------
// BK=64 (half the K-steps/barrier-drains of the BK=32 m97 form). LDS staged via
// global_load_lds with the XOR swizzle kc^=(row&7) baked into the GLOBAL source
// address (linear LDS dest, rule 21); reads apply the same involution, which
// folds to a lane-constant -> frag reads drop from 8/16-way conflicts to 2-way.
template<int OUT_F32>
__global__ __launch_bounds__(256)
void gemm_bt(const bf16* __restrict__ A, const bf16* __restrict__ BT,
             const float* __restrict__ bias, void* __restrict__ out,
             int M, int N, int K)
{
    __shared__ __align__(16) bf16 As[128 * 64];
    __shared__ __align__(16) bf16 Bs[128 * 64];
    int tid = threadIdx.x;
    int lane = tid & 63, w = tid >> 6;
    int wm = w & 1, wn = w >> 1;
    int nwg  = gridDim.x * gridDim.y;
    int wgid = xcd_swz(blockIdx.y * gridDim.x + blockIdx.x, nwg);
    int m0 = (wgid % gridDim.x) * 128, n0 = (wgid / gridDim.x) * 128;
    int lq = lane & 15, lk = lane >> 4;

    // lane-constant swizzled k-chunk byte offsets for the two K=32 halves
    int kx0 = ((lk ^ (lq & 7)) << 4);
    int kx1 = (((4 + lk) ^ (lq & 7)) << 4);

    f32x4 acc[4][4] = {};

    for (int k0 = 0; k0 < K; k0 += 64) {
        __syncthreads();
#pragma unroll
        for (int j = 0; j < 4; ++j) {
            int c = j * 256 + tid;              // chunk 0..1023 per operand
            int row = c >> 3, kc = c & 7;
            int koff = k0 + ((kc ^ (row & 7)) << 3);
            gload_lds16(A  + (size_t)(m0 + row) * K + koff, (char*)As + c * 16);
            gload_lds16(BT + (size_t)(n0 + row) * K + koff, (char*)Bs + c * 16);
        }
        __syncthreads();
#pragma unroll
        for (int ks = 0; ks < 2; ++ks) {
            int kx = ks ? kx1 : kx0;
            bf16x8 af[4], bfr[4];
#pragma unroll
            for (int m = 0; m < 4; ++m)
                af[m] = *(const bf16x8*)((char*)As + (wm * 64 + m * 16 + lq) * 128 + kx);
#pragma unroll
            for (int n = 0; n < 4; ++n)
                bfr[n] = *(const bf16x8*)((char*)Bs + (wn * 64 + n * 16 + lq) * 128 + kx);
#pragma unroll
            for (int m = 0; m < 4; ++m)
#pragma unroll
                for (int n = 0; n < 4; ++n)
                    acc[m][n] = __builtin_amdgcn_mfma_f32_16x16x32_bf16(af[m], bfr[n], acc[m][n], 0, 0, 0);
        }
    }

    int rb = m0 + wm * 64, cb = n0 + wn * 64;
#pragma unroll
    for (int m = 0; m < 4; ++m) {
#pragma unroll
        for (int n = 0; n < 4; ++n) {
            int col = cb + n * 16 + lq;
            float b = bias[col];
#pragma unroll
            for (int r = 0; r < 4; ++r) {
                int row = rb + m * 16 + lk * 4 + r;
                float v = acc[m][n][r] + b;
                if (OUT_F32) ((float*)out)[(size_t)row * N + col] = v;
                else         ((bf16*)out)[(size_t)row * N + col] = (bf16)v;
            }
        }
    }
}

// ---------------- fused pack: RoPE Q/K + V-transpose into KVp tile images ----------------
// blocks [0,32768): rope; [32768,33792): V pack.
// KVp[h][t][14336]: 0..8191 K image (chunk = key*16 + (dchunk^(key&15)));
// 8192..14335 V image (chunk d*8+cpos holds keys (cpos^(d&7))*8.. at dim d;
// d 0..71 data, 72 ones (l via MFMA), 73..95 zero).
__global__ __launch_bounds__(256)
void pack(const bf16* __restrict__ qkv, const float* __restrict__ cs,
          const float* __restrict__ sn, bf16* __restrict__ Qp,
          bf16* __restrict__ KVp)
{
    __shared__ __align__(16) bf16 tl[64][80];
    int b = blockIdx.x, tid = threadIdx.x;
    if (b < 32768) {
        int idx = b * 256 + tid;                 // NH*SEQ*128
        int dd = idx & 127;
        int s  = (idx >> 7) & (SEQ - 1);
        int h  = idx >> 19;
        float qv = 0.f, kv = 0.f;
        if (dd < HD) {
            const bf16* row = qkv + (size_t)s * N3 + h * HD;
            float c  = cs[s * HD + dd], si = sn[s * HD + dd];
            int   dp = (dd < 36) ? dd + 36 : dd - 36;
            float sg = (dd < 36) ? -1.f : 1.f;
            float qa = (float)row[dd],       qb = (float)row[dp];
            float ka = (float)row[HID + dd], kb = (float)row[HID + dp];
            qv = (qa * c + sg * qb * si) * (0.11785113019775793f * 1.4426950408889634f);
            kv =  ka * c + sg * kb * si;
        }
        int t = s >> 6, key = s & 63;
        int chunk = key * 16 + ((dd >> 3) ^ (key & 15));
        KVp[((size_t)(h * 64 + t)) * TILE_ELEMS + chunk * 8 + (dd & 7)] = (bf16)kv;
        if (dd < DQ) Qp[((size_t)h * SEQ + s) * DQ + dd] = (bf16)qv;
        return;
    }
    int bb = b - 32768;
    int t = bb & 63, h = bb >> 6, s0 = t * 64;
    for (int i = tid; i < 64 * 9; i += 256) {
        int key = i / 9, c8 = (i % 9) * 8;
        *(bf16x8*)&tl[key][c8] =
            *(const bf16x8*)&qkv[(size_t)(s0 + key) * N3 + 2 * HID + h * HD + c8];
    }
    __syncthreads();
    bf16* dst = KVp + ((size_t)(h * 64 + t)) * TILE_ELEMS + 8192;
    for (int vcid = tid; vcid < 768; vcid += 256) {     // 96 rows x 8 chunks
        int d = vcid >> 3, cpos = vcid & 7;
        int kb8 = (cpos ^ (d & 7)) << 3;
        bf16x8 v;
#pragma unroll
        for (int j = 0; j < 8; ++j)
            v[j] = (d < HD) ? tl[kb8 + j][d] : ((d == HD) ? (bf16)1.f : (bf16)0.f);
        *(bf16x8*)&dst[vcid * 8] = v;
    }
}

// ---- flash attention: 8 waves x 32q, 3-buffer rotation, T15 within-wave pipeline ----
// Block mapping: each XCD owns exactly 2 heads (KVp working set 3.7MB -> L2-resident).
// No-max softmax (scores bounded, shift-invariant); l via ones-row of V.
__global__ __launch_bounds__(512, 2)
void attn_fwd11(const bf16* __restrict__ Qp, const bf16* __restrict__ KVp,
                bf16* __restrict__ Oout)
{
    __shared__ __align__(16) char smem[86016];   // 3 x 28672

    // head-locality mapping: XCD x = o&7 serves heads {2x, 2x+1}
    const int o = blockIdx.x;
    const int x = o & 7, s = o >> 3;             // s in [0,32)
    const int h  = x * 2 + (s >> 4);
    const int q0 = (s & 15) * QBLK;
    const int tid = threadIdx.x, lane = tid & 63, w = tid >> 6;
    const int ql = lane & 31, hi = lane >> 5;
    const int q  = q0 + w * 32 + ql;

    // Q fragments (B-operand): Qf[ks][j] = Q[q][ks*16 + hi*8 + j]
    bf16x8 qf[5];
    const bf16* qbase = Qp + ((size_t)h * SEQ + q) * DQ + hi * 8;
#pragma unroll
    for (int ks = 0; ks < 5; ++ks) qf[ks] = *(const bf16x8*)(qbase + ks * 16);

    // precomputed swizzled tile-relative LDS byte-offsets
    int aK[5], aV[4];
#pragma unroll
    for (int ks = 0; ks < 5; ++ks)
        aK[ks] = ql * 256 + (((ks * 2 + hi) ^ (ql & 15)) * 16);
#pragma unroll
    for (int u = 0; u < 4; ++u)
        aV[u] = 16384 + ql * 128 + (((u * 2 + hi) ^ (ql & 7)) * 16);

    f32x16 o_[3] = {};           // O^T accum; V row 72 (ones) carries l

    const bf16* kvbase = KVp + (size_t)h * (64 * TILE_ELEMS) + (size_t)tid * 8;

    // stage tile T into buffer at byte DB: 1792 x 16B chunks; tid<256 take 4, else 3
#define STAGE(T, DB) do {                                                      \
        const bf16* s_ = kvbase + (size_t)(T) * TILE_ELEMS;                    \
        char* d_ = smem + (DB) + tid * 16;                                     \
        _Pragma("unroll")                                                      \
        for (int j_ = 0; j_ < 3; ++j_)                                         \
            gload_lds16(s_ + j_ * 4096, d_ + j_ * 8192);                       \
        if (tid < 256) gload_lds16(s_ + 12288, d_ + 24576);                    \
    } while (0)

    auto qk = [&](const char* bK, f32x16& sa, f32x16& sb) {
        __builtin_amdgcn_s_setprio(1);
#pragma unroll
        for (int ks = 0; ks < 5; ++ks) {
            bf16x8 kf = *(const bf16x8*)(bK + aK[ks]);
            sa = __builtin_amdgcn_mfma_f32_32x32x16_bf16(kf, qf[ks], sa, 0, 0, 0);
        }
#pragma unroll
        for (int ks = 0; ks < 5; ++ks) {
            bf16x8 kf = *(const bf16x8*)(bK + 8192 + aK[ks]);
            sb = __builtin_amdgcn_mfma_f32_32x32x16_bf16(kf, qf[ks], sb, 0, 0, 0);
        }
        __builtin_amdgcn_s_setprio(0);
    };

    auto expv = [&](const f32x16& sa, const f32x16& sb, const char* bV) {
        uint32_t wd[16];
#pragma unroll
        for (int i = 0; i < 8; ++i) {
            wd[i]   = (uint32_t)bfbits(EXP2F(sa[2*i])) | ((uint32_t)bfbits(EXP2F(sa[2*i+1])) << 16);
            wd[8+i] = (uint32_t)bfbits(EXP2F(sb[2*i])) | ((uint32_t)bfbits(EXP2F(sb[2*i+1])) << 16);
        }
        PLSWAP(wd[0], wd[2]);   PLSWAP(wd[1], wd[3]);
        PLSWAP(wd[4], wd[6]);   PLSWAP(wd[5], wd[7]);
        PLSWAP(wd[8], wd[10]);  PLSWAP(wd[9], wd[11]);
        PLSWAP(wd[12], wd[14]); PLSWAP(wd[13], wd[15]);
        u32x4 u0 = {wd[0],wd[1],wd[2],wd[3]},   u1 = {wd[4],wd[5],wd[6],wd[7]};
        u32x4 u2 = {wd[8],wd[9],wd[10],wd[11]}, u3 = {wd[12],wd[13],wd[14],wd[15]};
        bf16x8 pb[4] = { __builtin_bit_cast(bf16x8, u0), __builtin_bit_cast(bf16x8, u1),
                         __builtin_bit_cast(bf16x8, u2), __builtin_bit_cast(bf16x8, u3) };
        __builtin_amdgcn_s_setprio(1);
#pragma unroll
        for (int db = 0; db < 3; ++db)
#pragma unroll
            for (int u = 0; u < 4; ++u) {
                bf16x8 vf = *(const bf16x8*)(bV + db * 4096 + aV[u]);
                o_[db] = __builtin_amdgcn_mfma_f32_32x32x16_bf16(vf, pb[u], o_[db], 0, 0, 0);
            }
        __builtin_amdgcn_s_setprio(0);
    };

    f32x16 pa = {}, pb_ = {};    // previous tile's scores (pipeline state)

    STAGE(0, 0);
    asm volatile("s_waitcnt vmcnt(0)" ::: "memory");
    __builtin_amdgcn_s_barrier();
    STAGE(1, 28672);
    qk(smem, pa, pb_);
    asm volatile("s_waitcnt vmcnt(0)" ::: "memory");
    __builtin_amdgcn_s_barrier();

#define BODY(T, KB, VB, SB) do {                                               \
        if ((T) < 63) STAGE((T) + 1, SB);                                      \
        f32x16 ca = {}, cb = {};                                               \
        qk(smem + (KB), ca, cb);                                               \
        expv(pa, pb_, smem + (VB));                                            \
        pa = ca; pb_ = cb;                                                     \
        __builtin_amdgcn_sched_barrier(0);                                     \
        asm volatile("s_waitcnt vmcnt(0)" ::: "memory");                       \
        __builtin_amdgcn_s_barrier();                                          \
    } while (0)

    for (int t = 1; t < 64; t += 3) {
        BODY(t,     28672, 0,     57344);
        BODY(t + 1, 57344, 28672, 0);
        BODY(t + 2, 0,     57344, 28672);
    }
    expv(pa, pb_, smem);         // drain: tile 63 (V resident in buffer 0)
#undef BODY
#undef STAGE

    // ---- epilogue: LDS transpose (stride 82 = 41 words, odd -> conflict-free) ----
    __syncthreads();
    bf16* Os = (bf16*)smem;                        // [QBLK][82]
    {
        float lv  = o_[2][4];                      // d=72 row holds l (hi=0 lanes)
        float lo_ = __shfl_xor(lv, 32);
        float invl = 1.0f / (hi ? lo_ : lv);
        int qloc = w * 32 + ql;
#pragma unroll
        for (int db = 0; db < 3; ++db)
#pragma unroll
            for (int r = 0; r < 16; ++r) {
                int dloc = (r & 3) + 8 * (r >> 2) + 4 * hi;
                int d = db * 32 + dloc;
                if (d < HD) Os[qloc * 82 + d] = (bf16)(o_[db][r] * invl);
            }
    }
    __syncthreads();
    for (int i = tid; i < QBLK * 36; i += 512) {
        int row = i / 36, c = i % 36;
        uint32_t val = *(const uint32_t*)((const char*)Os + row * 164 + c * 4);
        *(uint32_t*)((char*)Oout + (size_t)(q0 + row) * 2304 + h * 144 + c * 4) = val;
    }
}

extern "C" void kernel_launch(void* const* d_in, const int* in_sizes, int n_in,
                              void* d_out, int out_size, void* d_ws, size_t ws_size,
                              hipStream_t stream)
{
    const float* hidden = (const float*)d_in[0];
    // d_in[1] = cu_seqlens: unused by the reference
    const float* cosT  = (const float*)d_in[2];
    const float* sinT  = (const float*)d_in[3];
    const float* Wqkv  = (const float*)d_in[4];
    const float* bqkv  = (const float*)d_in[5];
    const float* Wproj = (const float*)d_in[6];
    const float* bproj = (const float*)d_in[7];

    char* ws = (char*)d_ws;
    size_t off = 0;
    auto alloc = [&](size_t bytes) {
        char* p = ws + off;
        off += (bytes + 255) & ~(size_t)255;
        return p;
    };
    bf16* hid_b  = (bf16*)alloc((size_t)SEQ * HID * 2);
    bf16* WqkvT  = (bf16*)alloc((size_t)N3  * HID * 2);
    bf16* WprojT = (bf16*)alloc((size_t)HID * HID * 2);
    bf16* qkv_b  = (bf16*)alloc((size_t)SEQ * N3  * 2);
    bf16* Qp     = (bf16*)alloc((size_t)NH * SEQ * DQ * 2);
    bf16* KVp    = (bf16*)alloc((size_t)NH * 64 * TILE_ELEMS * 2);
    bf16* attno  = hid_b;  // overlay: hid_b dead after GEMM1

    prep<<<7488, 256, 0, stream>>>(hidden, Wqkv, Wproj, hid_b, WqkvT, WprojT);
    gemm_bt<0><<<dim3(SEQ / 128, N3 / 128), 256, 0, stream>>>(hid_b, WqkvT, bqkv, qkv_b,
                                                              SEQ, N3, HID);
    pack<<<33792, 256, 0, stream>>>(qkv_b, cosT, sinT, Qp, KVp);
    attn_fwd11<<<dim3(SEQ / QBLK * NH), 512, 0, stream>>>(Qp, KVp, attno);
    gemm_bt<1><<<dim3(SEQ / 128, HID / 128), 256, 0, stream>>>(attno, WprojT, bproj, d_out,
                                                               SEQ, HID, HID);
}